// Round 2
// baseline (2182.805 us; speedup 1.0000x reference)
//
#include <hip/hip_runtime.h>
#include <hip/hip_bf16.h>
#include <cstdint>
#include <cstddef>

// ---- problem constants ----
#define B_N       4
#define C_INCH    23
#define T_N       8
#define W_IMG     128
#define L_SEQ     8192
#define BLROWS    32768      // B_N * L_SEQ
#define DM_       256
#define D_INNER_  512
#define CONV_DIM_ 544
#define D_PROJ    1064
#define KPATCH    368        // C_INCH*4*4
#define NHEADS_   8
#define QCH       128        // scan chunk length
#define NCH       64         // chunks per batch

typedef unsigned short ushort_t;
typedef unsigned int uint_t;

__device__ __forceinline__ float b2f(ushort_t u) {
    union { float f; uint_t u; } v; v.u = ((uint_t)u) << 16; return v.f;
}
__device__ __forceinline__ ushort_t f2b(float f) {
    union { float f; uint_t u; } v; v.f = f;
    uint_t r = v.u + 0x7fffu + ((v.u >> 16) & 1u);
    return (ushort_t)(r >> 16);
}
// uint holding 2 packed bf16 -> (elem0, elem1) as floats
__device__ __forceinline__ float2 bpair(uint_t u) {
    union { float f; uint_t u; } a, b;
    a.u = u << 16; b.u = u & 0xffff0000u;
    return make_float2(a.f, b.f);
}

// ---------------------------------------------------------------
// small transpose: src[d][k] (256 x 368) -> dst[k][d] (368 x 256)
__global__ void k_transpose(const float* __restrict__ src, float* __restrict__ dst) {
    int k = blockIdx.x;       // 0..367
    int d = threadIdx.x;      // 0..255
    dst[k * 256 + d] = src[d * KPATCH + k];
}

// ---------------------------------------------------------------
// patch embed -> xs (bf16). one block per (b,t,hp): 32 rows (wp) x 256 cols (d)
__global__ void __launch_bounds__(256) k_patch(const float* __restrict__ x,
                                               const float* __restrict__ wt,  // [k][d]
                                               const float* __restrict__ pb,
                                               ushort_t* __restrict__ xs) {
    __shared__ float Alds[KPATCH * 36];
    int hp = blockIdx.x, t = blockIdx.y, b = blockIdx.z;
    int tid = threadIdx.x;
    int half = tid >> 7;       // 0/1
    int q = tid & 127;         // 0..127 (w coordinate)
    for (int s2 = 0; s2 < 46; ++s2) {
        int seg = s2 * 2 + half;            // 0..91 = c*4 + i
        int c = seg >> 2, i = seg & 3;
        float v = x[(((size_t)(b * C_INCH + c) * T_N + t) << 14) + (size_t)(hp * 4 + i) * W_IMG + q];
        Alds[(c * 16 + i * 4 + (q & 3)) * 36 + (q >> 2)] = v;
    }
    __syncthreads();

    float acc[32];
    #pragma unroll
    for (int r = 0; r < 32; ++r) acc[r] = 0.f;
    int d = tid;
    for (int k = 0; k < KPATCH; ++k) {
        float wv = wt[k * 256 + d];
        const float4* a4p = (const float4*)&Alds[k * 36];
        #pragma unroll
        for (int r0 = 0; r0 < 8; ++r0) {
            float4 a4 = a4p[r0];
            acc[r0 * 4 + 0] += a4.x * wv;
            acc[r0 * 4 + 1] += a4.y * wv;
            acc[r0 * 4 + 2] += a4.z * wv;
            acc[r0 * 4 + 3] += a4.w * wv;
        }
    }
    float pbv = pb[d];
    size_t rowbase = (size_t)b * L_SEQ + t * 1024 + hp * 32;
    #pragma unroll
    for (int wp = 0; wp < 32; ++wp) {
        xs[(rowbase + wp) * DM_ + d] = f2b(acc[wp] + pbv);
    }
}

// ---------------------------------------------------------------
// generic GEMM: C[M,N] = A[M,K] @ W[K,N], 32 rows x 256 cols per block.
// A/C addressed with runtime lda/ldc + column offsets (lets us pack into zx).
template <int K, int N, bool ABF, bool CBF>
__global__ void __launch_bounds__(256) k_gemm(const void* __restrict__ Av, int lda, int aoff,
                                              const float* __restrict__ W,
                                              void* __restrict__ Cv, int ldc, int coff) {
    __shared__ float Alds[256 * 36];
    int rowbase = blockIdx.y * 32;
    int col = blockIdx.x * 256 + threadIdx.x;
    int colc = (col < N) ? col : (N - 1);
    float acc[32];
    #pragma unroll
    for (int r = 0; r < 32; ++r) acc[r] = 0.f;

    for (int k0 = 0; k0 < K; k0 += 256) {
        __syncthreads();
        // stage A tile [k=256][r=32], layout Alds[k*36 + r]
        #pragma unroll 4
        for (int rr = 0; rr < 32; ++rr) {
            size_t aidx = (size_t)(rowbase + rr) * lda + aoff + k0 + threadIdx.x;
            float av;
            if (ABF) av = b2f(((const ushort_t*)Av)[aidx]);
            else     av = ((const float*)Av)[aidx];
            Alds[threadIdx.x * 36 + rr] = av;
        }
        __syncthreads();
        for (int k = 0; k < 256; ++k) {
            float wv = W[(size_t)(k0 + k) * N + colc];
            const float4* a4p = (const float4*)&Alds[k * 36];
            #pragma unroll
            for (int r0 = 0; r0 < 8; ++r0) {
                float4 a4 = a4p[r0];
                acc[r0 * 4 + 0] += a4.x * wv;
                acc[r0 * 4 + 1] += a4.y * wv;
                acc[r0 * 4 + 2] += a4.z * wv;
                acc[r0 * 4 + 3] += a4.w * wv;
            }
        }
    }
    if (col < N) {
        #pragma unroll
        for (int r = 0; r < 32; ++r) {
            size_t cidx = (size_t)(rowbase + r) * ldc + coff + col;
            if (CBF) ((ushort_t*)Cv)[cidx] = f2b(acc[r]);
            else     ((float*)Cv)[cidx] = acc[r];
        }
    }
}

// ---------------------------------------------------------------
// causal depthwise conv (kernel 4) + silu over 544 channels -> xbc (bf16),
// plus dt softplus/dA.
__global__ void __launch_bounds__(256) k_conv(const float* __restrict__ zx,
                                              const float* __restrict__ cw,
                                              const float* __restrict__ cb,
                                              const float* __restrict__ dtb,
                                              const float* __restrict__ alog,
                                              ushort_t* __restrict__ xbc,
                                              float* __restrict__ dtv,
                                              float* __restrict__ dAv) {
    int row = blockIdx.x;            // 0..BLROWS-1
    int l = row & (L_SEQ - 1);
    for (int ch = threadIdx.x; ch < 552; ch += 256) {
        if (ch < CONV_DIM_) {
            float acc = cb[ch];
            #pragma unroll
            for (int k = 0; k < 4; ++k) {
                int lo = l + k - 3;
                if (lo >= 0) {
                    acc += zx[(size_t)(row + k - 3) * D_PROJ + D_INNER_ + ch] * cw[ch * 4 + k];
                }
            }
            float s = acc / (1.f + __expf(-acc));   // silu
            xbc[(size_t)row * CONV_DIM_ + ch] = f2b(s);
        } else {
            int h = ch - CONV_DIM_;
            float v = zx[(size_t)row * D_PROJ + (D_INNER_ + CONV_DIM_) + h] + dtb[h];
            float sp = (v > 20.f) ? v : log1pf(__expf(v));
            float A = -__expf(alog[h]);
            dtv[row * 8 + h] = sp;
            dAv[row * 8 + h] = __expf(sp * A);
        }
    }
}

// ---------------------------------------------------------------
// chunked scan phase 1: per-chunk local scan from zero state.
// block = (chunk c, head h, batch b); 256 thr: p = tid>>2 (0..63), nq = tid&3
// y written into zx columns 512..1023 (dead after k_conv).
__global__ void __launch_bounds__(256) k_scan_chunk(const ushort_t* __restrict__ xbc,
                                                    const float* __restrict__ dtv,
                                                    const float* __restrict__ dAv,
                                                    const float* __restrict__ Dp,
                                                    float* __restrict__ zx,     // y dest
                                                    float* __restrict__ cdv,
                                                    float* __restrict__ sbuf) {
    int c = blockIdx.x, h = blockIdx.y, b = blockIdx.z;
    int tid = threadIdx.x;
    int p = tid >> 2, nq = tid & 3;
    float h0 = 0.f, h1 = 0.f, h2 = 0.f, h3 = 0.f;
    float cd = 1.f;
    float Dh = Dp[h];
    size_t row0 = (size_t)b * L_SEQ + (size_t)c * QCH;
    for (int s = 0; s < QCH; ++s) {
        size_t row = row0 + s;
        float da  = dAv[row * 8 + h];
        float dtt = dtv[row * 8 + h];
        float xh  = b2f(xbc[row * CONV_DIM_ + h * 64 + p]);
        const uint_t* bc = (const uint_t*)(xbc + row * CONV_DIM_ + 512);
        float2 Bl = bpair(bc[nq * 2 + 0]);
        float2 Bh = bpair(bc[nq * 2 + 1]);
        float2 Cl = bpair(bc[8 + nq * 2 + 0]);
        float2 Ch = bpair(bc[8 + nq * 2 + 1]);
        float xdt = xh * dtt;
        h0 = da * h0 + xdt * Bl.x;
        h1 = da * h1 + xdt * Bl.y;
        h2 = da * h2 + xdt * Bh.x;
        h3 = da * h3 + xdt * Bh.y;
        float part = h0 * Cl.x + h1 * Cl.y + h2 * Ch.x + h3 * Ch.y;
        part += __shfl_xor(part, 1);
        part += __shfl_xor(part, 2);
        cd *= da;
        if (nq == 0) zx[row * D_PROJ + 512 + h * 64 + p] = part + Dh * xh;
        if (tid == 0) cdv[row * 8 + h] = cd;
    }
    // store chunk-final local state (64x16 per block), fully coalesced
    float4 st = make_float4(h0, h1, h2, h3);
    *(float4*)&sbuf[(((size_t)(b * 8 + h) * NCH + c) << 10) + tid * 4] = st;
}

// ---------------------------------------------------------------
// phase 2: sequential chain over chunks (tiny). block = (h, b); thread holds 4 states.
__global__ void __launch_bounds__(256) k_chain(const float* __restrict__ sbuf,
                                               const float* __restrict__ cdv,
                                               float* __restrict__ hin) {
    int h = blockIdx.x, b = blockIdx.y;
    int tid = threadIdx.x;
    float4 H = make_float4(0.f, 0.f, 0.f, 0.f);
    size_t base = ((size_t)(b * 8 + h) * NCH) << 10;
    for (int c = 0; c < NCH; ++c) {
        *(float4*)&hin[base + ((size_t)c << 10) + tid * 4] = H;   // incoming state of chunk c
        float cdf = cdv[((size_t)b * L_SEQ + (size_t)c * QCH + (QCH - 1)) * 8 + h];
        float4 S = *(const float4*)&sbuf[base + ((size_t)c << 10) + tid * 4];
        H.x = cdf * H.x + S.x;
        H.y = cdf * H.y + S.y;
        H.z = cdf * H.z + S.z;
        H.w = cdf * H.w + S.w;
    }
}

// ---------------------------------------------------------------
// phase 3: y[b,l,h,p] += cumdecay * (C[l] . Hin[b,h,chunk(l),p,:]); y lives in zx cols 512+
__global__ void __launch_bounds__(256) k_fixup(const ushort_t* __restrict__ xbc,
                                               const float* __restrict__ cdv,
                                               const float* __restrict__ hin,
                                               float* __restrict__ zx) {
    size_t g = (size_t)blockIdx.x * 256 + threadIdx.x;   // over BLROWS*512
    int p = (int)(g & 63);
    int h = (int)((g >> 6) & 7);
    size_t row = g >> 9;
    int b = (int)(row >> 13);
    int l = (int)(row & (L_SEQ - 1));
    int c = l >> 7;   // QCH=128
    float cd = cdv[row * 8 + h];
    const float* Hrow = &hin[(((size_t)(b * 8 + h) * NCH + c) << 10) + p * 16];
    const uint_t* Cp = (const uint_t*)(xbc + row * CONV_DIM_ + 528);
    float dot = 0.f;
    #pragma unroll
    for (int n4 = 0; n4 < 4; ++n4) {
        float4 Hv = *(const float4*)&Hrow[n4 * 4];
        float2 c0 = bpair(Cp[n4 * 2 + 0]);
        float2 c1 = bpair(Cp[n4 * 2 + 1]);
        dot += Hv.x * c0.x + Hv.y * c0.y + Hv.z * c1.x + Hv.w * c1.y;
    }
    zx[row * D_PROJ + 512 + (int)(g & 511)] += cd * dot;
}

// ---------------------------------------------------------------
// gate (silu(z)) + RMSNorm, in-place on y (zx cols 512..1023). block = one row.
__global__ void __launch_bounds__(256) k_norm(float* __restrict__ zx,
                                              const float* __restrict__ nw) {
    int row = blockIdx.x;
    int tid = threadIdx.x;
    size_t rb = (size_t)row * D_PROJ;
    float yv0 = zx[rb + 512 + tid];
    float yv1 = zx[rb + 768 + tid];
    float z0 = zx[rb + tid];
    float z1 = zx[rb + 256 + tid];
    float yg0 = yv0 * (z0 / (1.f + __expf(-z0)));
    float yg1 = yv1 * (z1 / (1.f + __expf(-z1)));
    float sq = yg0 * yg0 + yg1 * yg1;
    #pragma unroll
    for (int off = 32; off >= 1; off >>= 1) sq += __shfl_xor(sq, off);
    __shared__ float wsum[4];
    int wid = tid >> 6;
    if ((tid & 63) == 0) wsum[wid] = sq;
    __syncthreads();
    float tot = wsum[0] + wsum[1] + wsum[2] + wsum[3];
    float scale = rsqrtf(tot * (1.f / 512.f) + 1e-5f);
    zx[rb + 512 + tid] = yg0 * scale * nw[tid];
    zx[rb + 768 + tid] = yg1 * scale * nw[256 + tid];
}

// ---------------------------------------------------------------
// unembed + bias + residual. one block per (b,t,hp); 32 wp rows x 256 d staged in LDS.
__global__ void __launch_bounds__(256) k_unembed(const ushort_t* __restrict__ es, // out_seq bf16 [BL][256]
                                                 const float* __restrict__ wtu,   // [k=368][d=256]
                                                 const float* __restrict__ ub,
                                                 const float* __restrict__ xin,
                                                 float* __restrict__ out) {
    __shared__ float ES[32 * 260];
    int hp = blockIdx.x, t = blockIdx.y, b = blockIdx.z;
    int tid = threadIdx.x;
    size_t rowbase = (size_t)b * L_SEQ + t * 1024 + hp * 32;
    for (int wp = 0; wp < 32; ++wp) ES[wp * 260 + tid] = b2f(es[(rowbase + wp) * DM_ + tid]);
    __syncthreads();

    int w = tid & 127;
    int ci2 = tid >> 7;
    int j = w & 3, r = w >> 2;
    const float4* ES4 = (const float4*)&ES[r * 260];
    for (int ci = ci2; ci < 92; ci += 2) {
        int kk = ci * 4 + j;                       // = c*16 + i*4 + j
        const float4* W4 = (const float4*)&wtu[(size_t)kk * 256];
        float acc = 0.f;
        #pragma unroll 8
        for (int d4 = 0; d4 < 64; ++d4) {
            float4 a = ES4[d4];
            float4 wv = W4[d4];
            acc += a.x * wv.x + a.y * wv.y + a.z * wv.z + a.w * wv.w;
        }
        int c = ci >> 2, i = ci & 3;
        size_t oidx = (((size_t)(b * C_INCH + c) * T_N + t) << 14) + (size_t)(hp * 4 + i) * W_IMG + w;
        out[oidx] = acc + ub[c] + xin[oidx];
    }
}

// ---------------------------------------------------------------
extern "C" void kernel_launch(void* const* d_in, const int* in_sizes, int n_in,
                              void* d_out, int out_size, void* d_ws, size_t ws_size,
                              hipStream_t stream) {
    const float* x       = (const float*)d_in[0];
    const float* patch_w = (const float*)d_in[1];
    const float* patch_b = (const float*)d_in[2];
    const float* W_in    = (const float*)d_in[3];
    const float* conv_w  = (const float*)d_in[4];
    const float* conv_b  = (const float*)d_in[5];
    const float* dt_bias = (const float*)d_in[6];
    const float* A_log   = (const float*)d_in[7];
    const float* D_param = (const float*)d_in[8];
    const float* norm_w  = (const float*)d_in[9];
    const float* W_out   = (const float*)d_in[10];
    const float* unemb_w = (const float*)d_in[11];
    const float* unemb_b = (const float*)d_in[12];
    float* out = (float*)d_out;

    // ---- workspace carve (bytes) ----
    char* p = (char*)d_ws;
    float* zx   = (float*)p;   p += (size_t)BLROWS * D_PROJ * 4;      // 139.5 MB (z | xBC->y | dt)
    float* dtv  = (float*)p;   p += (size_t)BLROWS * 8 * 4;
    float* dAv  = (float*)p;   p += (size_t)BLROWS * 8 * 4;
    float* cdv  = (float*)p;   p += (size_t)BLROWS * 8 * 4;
    float* sbuf = (float*)p;   p += (size_t)32 * NCH * 1024 * 4;      // 8.4 MB
    float* hin  = (float*)p;   p += (size_t)32 * NCH * 1024 * 4;      // 8.4 MB
    float* wtp  = (float*)p;   p += (size_t)KPATCH * DM_ * 4;
    float* wtu  = (float*)p;   p += (size_t)KPATCH * DM_ * 4;
    ushort_t* xs  = (ushort_t*)p; p += (size_t)BLROWS * DM_ * 2;      // 16.8 MB (bf16)
    ushort_t* xbc = (ushort_t*)p; p += (size_t)BLROWS * CONV_DIM_ * 2;// 35.7 MB (bf16)
    size_t need = (size_t)(p - (char*)d_ws);
    if (ws_size < need) return;   // deterministic no-op -> clean absmax fail = diagnostic

    k_transpose<<<KPATCH, 256, 0, stream>>>(patch_w, wtp);
    k_transpose<<<KPATCH, 256, 0, stream>>>(unemb_w, wtu);

    k_patch<<<dim3(32, 8, 4), 256, 0, stream>>>(x, wtp, patch_b, xs);

    // in-proj: zx[BL,1064] = xs[BL,256] @ W_in
    k_gemm<256, 1064, true, false><<<dim3(5, 1024), 256, 0, stream>>>(xs, 256, 0, W_in, zx, D_PROJ, 0);

    k_conv<<<BLROWS, 256, 0, stream>>>(zx, conv_w, conv_b, dt_bias, A_log, xbc, dtv, dAv);

    k_scan_chunk<<<dim3(NCH, 8, 4), 256, 0, stream>>>(xbc, dtv, dAv, D_param, zx, cdv, sbuf);
    k_chain<<<dim3(8, 4), 256, 0, stream>>>(sbuf, cdv, hin);
    k_fixup<<<65536, 256, 0, stream>>>(xbc, cdv, hin, zx);

    k_norm<<<BLROWS, 256, 0, stream>>>(zx, norm_w);

    // out-proj: out_seq[BL,256] = y[BL,512] @ W_out ; y lives in zx cols 512..1023
    k_gemm<512, 256, false, true><<<dim3(1, 1024), 256, 0, stream>>>(zx, D_PROJ, 512, W_out, xs, DM_, 0);

    k_unembed<<<dim3(32, 8, 4), 256, 0, stream>>>(xs, wtu, unemb_b, x, out);
}

// Round 3
// 1025.910 us; speedup vs baseline: 2.1277x; 2.1277x over previous
//
#include <hip/hip_runtime.h>
#include <hip/hip_bf16.h>
#include <cstdint>
#include <cstddef>

// ---- problem constants ----
#define B_N       4
#define C_INCH    23
#define T_N       8
#define W_IMG     128
#define L_SEQ     8192
#define BLROWS    32768      // B_N * L_SEQ
#define DM_       256
#define D_INNER_  512
#define CONV_DIM_ 544
#define D_PROJ    1064
#define KPATCH    368        // C_INCH*4*4
#define NHEADS_   8
#define QCH       128        // scan chunk length
#define NCH       64         // chunks per batch

typedef unsigned short ushort_t;
typedef unsigned int uint_t;

__device__ __forceinline__ float b2f(ushort_t u) {
    union { float f; uint_t u; } v; v.u = ((uint_t)u) << 16; return v.f;
}
__device__ __forceinline__ ushort_t f2b(float f) {
    union { float f; uint_t u; } v; v.f = f;
    uint_t r = v.u + 0x7fffu + ((v.u >> 16) & 1u);
    return (ushort_t)(r >> 16);
}
// uint holding 2 packed bf16 -> (elem0, elem1) as floats
__device__ __forceinline__ float2 bpair(uint_t u) {
    union { float f; uint_t u; } a, b;
    a.u = u << 16; b.u = u & 0xffff0000u;
    return make_float2(a.f, b.f);
}

// ---------------------------------------------------------------
// small transpose: src[d][k] (256 x 368) -> dst[k][d] (368 x 256)
__global__ void k_transpose(const float* __restrict__ src, float* __restrict__ dst) {
    int k = blockIdx.x;       // 0..367
    int d = threadIdx.x;      // 0..255
    dst[k * 256 + d] = src[d * KPATCH + k];
}

// ---------------------------------------------------------------
// patch embed -> xs (bf16). one block per (b,t,hp): 32 rows (wp) x 256 cols (d)
__global__ void __launch_bounds__(256) k_patch(const float* __restrict__ x,
                                               const float* __restrict__ wt,  // [k][d]
                                               const float* __restrict__ pb,
                                               ushort_t* __restrict__ xs) {
    __shared__ float Alds[KPATCH * 36];
    int hp = blockIdx.x, t = blockIdx.y, b = blockIdx.z;
    int tid = threadIdx.x;
    int half = tid >> 7;       // 0/1
    int q = tid & 127;         // 0..127 (w coordinate)
    for (int s2 = 0; s2 < 46; ++s2) {
        int seg = s2 * 2 + half;            // 0..91 = c*4 + i
        int c = seg >> 2, i = seg & 3;
        float v = x[(((size_t)(b * C_INCH + c) * T_N + t) << 14) + (size_t)(hp * 4 + i) * W_IMG + q];
        Alds[(c * 16 + i * 4 + (q & 3)) * 36 + (q >> 2)] = v;
    }
    __syncthreads();

    float acc[32];
    #pragma unroll
    for (int r = 0; r < 32; ++r) acc[r] = 0.f;
    int d = tid;
    for (int k = 0; k < KPATCH; ++k) {
        float wv = wt[k * 256 + d];
        const float4* a4p = (const float4*)&Alds[k * 36];
        #pragma unroll
        for (int r0 = 0; r0 < 8; ++r0) {
            float4 a4 = a4p[r0];
            acc[r0 * 4 + 0] += a4.x * wv;
            acc[r0 * 4 + 1] += a4.y * wv;
            acc[r0 * 4 + 2] += a4.z * wv;
            acc[r0 * 4 + 3] += a4.w * wv;
        }
    }
    float pbv = pb[d];
    size_t rowbase = (size_t)b * L_SEQ + t * 1024 + hp * 32;
    #pragma unroll
    for (int wp = 0; wp < 32; ++wp) {
        xs[(rowbase + wp) * DM_ + d] = f2b(acc[wp] + pbv);
    }
}

// ---------------------------------------------------------------
// generic GEMM: C[M,N] = A[M,K] @ W[K,N], 32 rows x 256 cols per block.
// A/C addressed with runtime lda/ldc + column offsets (lets us pack into zx).
template <int K, int N, bool ABF, bool CBF>
__global__ void __launch_bounds__(256) k_gemm(const void* __restrict__ Av, int lda, int aoff,
                                              const float* __restrict__ W,
                                              void* __restrict__ Cv, int ldc, int coff) {
    __shared__ float Alds[256 * 36];
    int rowbase = blockIdx.y * 32;
    int col = blockIdx.x * 256 + threadIdx.x;
    int colc = (col < N) ? col : (N - 1);
    float acc[32];
    #pragma unroll
    for (int r = 0; r < 32; ++r) acc[r] = 0.f;

    for (int k0 = 0; k0 < K; k0 += 256) {
        __syncthreads();
        // stage A tile [k=256][r=32], layout Alds[k*36 + r]
        #pragma unroll 4
        for (int rr = 0; rr < 32; ++rr) {
            size_t aidx = (size_t)(rowbase + rr) * lda + aoff + k0 + threadIdx.x;
            float av;
            if (ABF) av = b2f(((const ushort_t*)Av)[aidx]);
            else     av = ((const float*)Av)[aidx];
            Alds[threadIdx.x * 36 + rr] = av;
        }
        __syncthreads();
        for (int k = 0; k < 256; ++k) {
            float wv = W[(size_t)(k0 + k) * N + colc];
            const float4* a4p = (const float4*)&Alds[k * 36];
            #pragma unroll
            for (int r0 = 0; r0 < 8; ++r0) {
                float4 a4 = a4p[r0];
                acc[r0 * 4 + 0] += a4.x * wv;
                acc[r0 * 4 + 1] += a4.y * wv;
                acc[r0 * 4 + 2] += a4.z * wv;
                acc[r0 * 4 + 3] += a4.w * wv;
            }
        }
    }
    if (col < N) {
        #pragma unroll
        for (int r = 0; r < 32; ++r) {
            size_t cidx = (size_t)(rowbase + r) * ldc + coff + col;
            if (CBF) ((ushort_t*)Cv)[cidx] = f2b(acc[r]);
            else     ((float*)Cv)[cidx] = acc[r];
        }
    }
}

// ---------------------------------------------------------------
// causal depthwise conv (kernel 4) + silu over 544 channels -> xbc (bf16),
// plus dt softplus/dA.
__global__ void __launch_bounds__(256) k_conv(const float* __restrict__ zx,
                                              const float* __restrict__ cw,
                                              const float* __restrict__ cb,
                                              const float* __restrict__ dtb,
                                              const float* __restrict__ alog,
                                              ushort_t* __restrict__ xbc,
                                              float* __restrict__ dtv,
                                              float* __restrict__ dAv) {
    int row = blockIdx.x;            // 0..BLROWS-1
    int l = row & (L_SEQ - 1);
    for (int ch = threadIdx.x; ch < 552; ch += 256) {
        if (ch < CONV_DIM_) {
            float acc = cb[ch];
            #pragma unroll
            for (int k = 0; k < 4; ++k) {
                int lo = l + k - 3;
                if (lo >= 0) {
                    acc += zx[(size_t)(row + k - 3) * D_PROJ + D_INNER_ + ch] * cw[ch * 4 + k];
                }
            }
            float s = acc / (1.f + __expf(-acc));   // silu
            xbc[(size_t)row * CONV_DIM_ + ch] = f2b(s);
        } else {
            int h = ch - CONV_DIM_;
            float v = zx[(size_t)row * D_PROJ + (D_INNER_ + CONV_DIM_) + h] + dtb[h];
            float sp = (v > 20.f) ? v : log1pf(__expf(v));
            float A = -__expf(alog[h]);
            dtv[row * 8 + h] = sp;
            dAv[row * 8 + h] = __expf(sp * A);
        }
    }
}

// ---------------------------------------------------------------
// chunked scan phase 1: per-chunk local scan from zero state.
// block = (chunk c, head h, batch b); 256 thr: p = tid>>2 (0..63), nq = tid&3
// y written into zx columns 512..1023 (dead after k_conv).
__global__ void __launch_bounds__(256) k_scan_chunk(const ushort_t* __restrict__ xbc,
                                                    const float* __restrict__ dtv,
                                                    const float* __restrict__ dAv,
                                                    const float* __restrict__ Dp,
                                                    float* __restrict__ zx,     // y dest
                                                    float* __restrict__ cdv,
                                                    float* __restrict__ sbuf) {
    int c = blockIdx.x, h = blockIdx.y, b = blockIdx.z;
    int tid = threadIdx.x;
    int p = tid >> 2, nq = tid & 3;
    float h0 = 0.f, h1 = 0.f, h2 = 0.f, h3 = 0.f;
    float cd = 1.f;
    float Dh = Dp[h];
    size_t row0 = (size_t)b * L_SEQ + (size_t)c * QCH;
    for (int s = 0; s < QCH; ++s) {
        size_t row = row0 + s;
        float da  = dAv[row * 8 + h];
        float dtt = dtv[row * 8 + h];
        float xh  = b2f(xbc[row * CONV_DIM_ + h * 64 + p]);
        const uint_t* bc = (const uint_t*)(xbc + row * CONV_DIM_ + 512);
        float2 Bl = bpair(bc[nq * 2 + 0]);
        float2 Bh = bpair(bc[nq * 2 + 1]);
        float2 Cl = bpair(bc[8 + nq * 2 + 0]);
        float2 Ch = bpair(bc[8 + nq * 2 + 1]);
        float xdt = xh * dtt;
        h0 = da * h0 + xdt * Bl.x;
        h1 = da * h1 + xdt * Bl.y;
        h2 = da * h2 + xdt * Bh.x;
        h3 = da * h3 + xdt * Bh.y;
        float part = h0 * Cl.x + h1 * Cl.y + h2 * Ch.x + h3 * Ch.y;
        part += __shfl_xor(part, 1);
        part += __shfl_xor(part, 2);
        cd *= da;
        if (nq == 0) zx[row * D_PROJ + 512 + h * 64 + p] = part + Dh * xh;
        if (tid == 0) cdv[row * 8 + h] = cd;
    }
    // store chunk-final local state (64x16 per block), fully coalesced
    float4 st = make_float4(h0, h1, h2, h3);
    *(float4*)&sbuf[(((size_t)(b * 8 + h) * NCH + c) << 10) + tid * 4] = st;
}

// ---------------------------------------------------------------
// phase 2: sequential chain over chunks (tiny). block = (h, b); thread holds 4 states.
__global__ void __launch_bounds__(256) k_chain(const float* __restrict__ sbuf,
                                               const float* __restrict__ cdv,
                                               float* __restrict__ hin) {
    int h = blockIdx.x, b = blockIdx.y;
    int tid = threadIdx.x;
    float4 H = make_float4(0.f, 0.f, 0.f, 0.f);
    size_t base = ((size_t)(b * 8 + h) * NCH) << 10;
    for (int c = 0; c < NCH; ++c) {
        *(float4*)&hin[base + ((size_t)c << 10) + tid * 4] = H;   // incoming state of chunk c
        float cdf = cdv[((size_t)b * L_SEQ + (size_t)c * QCH + (QCH - 1)) * 8 + h];
        float4 S = *(const float4*)&sbuf[base + ((size_t)c << 10) + tid * 4];
        H.x = cdf * H.x + S.x;
        H.y = cdf * H.y + S.y;
        H.z = cdf * H.z + S.z;
        H.w = cdf * H.w + S.w;
    }
}

// ---------------------------------------------------------------
// phase 3: y[b,l,h,p] += cumdecay * (C[l] . Hin[b,h,chunk(l),p,:]); y lives in zx cols 512+
__global__ void __launch_bounds__(256) k_fixup(const ushort_t* __restrict__ xbc,
                                               const float* __restrict__ cdv,
                                               const float* __restrict__ hin,
                                               float* __restrict__ zx) {
    size_t g = (size_t)blockIdx.x * 256 + threadIdx.x;   // over BLROWS*512
    int p = (int)(g & 63);
    int h = (int)((g >> 6) & 7);
    size_t row = g >> 9;
    int b = (int)(row >> 13);
    int l = (int)(row & (L_SEQ - 1));
    int c = l >> 7;   // QCH=128
    float cd = cdv[row * 8 + h];
    const float* Hrow = &hin[(((size_t)(b * 8 + h) * NCH + c) << 10) + p * 16];
    const uint_t* Cp = (const uint_t*)(xbc + row * CONV_DIM_ + 528);
    float dot = 0.f;
    #pragma unroll
    for (int n4 = 0; n4 < 4; ++n4) {
        float4 Hv = *(const float4*)&Hrow[n4 * 4];
        float2 c0 = bpair(Cp[n4 * 2 + 0]);
        float2 c1 = bpair(Cp[n4 * 2 + 1]);
        dot += Hv.x * c0.x + Hv.y * c0.y + Hv.z * c1.x + Hv.w * c1.y;
    }
    zx[row * D_PROJ + 512 + (int)(g & 511)] += cd * dot;
}

// ---------------------------------------------------------------
// gate (silu(z)) + RMSNorm, in-place on y (zx cols 512..1023). block = one row.
__global__ void __launch_bounds__(256) k_norm(float* __restrict__ zx,
                                              const float* __restrict__ nw) {
    int row = blockIdx.x;
    int tid = threadIdx.x;
    size_t rb = (size_t)row * D_PROJ;
    float yv0 = zx[rb + 512 + tid];
    float yv1 = zx[rb + 768 + tid];
    float z0 = zx[rb + tid];
    float z1 = zx[rb + 256 + tid];
    float yg0 = yv0 * (z0 / (1.f + __expf(-z0)));
    float yg1 = yv1 * (z1 / (1.f + __expf(-z1)));
    float sq = yg0 * yg0 + yg1 * yg1;
    #pragma unroll
    for (int off = 32; off >= 1; off >>= 1) sq += __shfl_xor(sq, off);
    __shared__ float wsum[4];
    int wid = tid >> 6;
    if ((tid & 63) == 0) wsum[wid] = sq;
    __syncthreads();
    float tot = wsum[0] + wsum[1] + wsum[2] + wsum[3];
    float scale = rsqrtf(tot * (1.f / 512.f) + 1e-5f);
    zx[rb + 512 + tid] = yg0 * scale * nw[tid];
    zx[rb + 768 + tid] = yg1 * scale * nw[256 + tid];
}

// ---------------------------------------------------------------
// scatter: out[b,c,t,h,w] = tmp[row(b,t,h>>2,w>>2), c*16+(h&3)*4+(w&3)] + ub[c] + x[...]
// grid: (h>>1, c*8+t, b), 256 threads = 2 h-values x 128 w.
__global__ void __launch_bounds__(256) k_scatter(const float* __restrict__ tmp,
                                                 const float* __restrict__ ub,
                                                 const float* __restrict__ xin,
                                                 float* __restrict__ out) {
    int tid = threadIdx.x;
    int w = tid & 127;
    int h = (blockIdx.x << 1) | (tid >> 7);
    int c = blockIdx.y >> 3, t = blockIdx.y & 7;
    int b = blockIdx.z;
    size_t row = (size_t)b * L_SEQ + t * 1024 + (h >> 2) * 32 + (w >> 2);
    int kk = c * 16 + (h & 3) * 4 + (w & 3);
    size_t oidx = (((size_t)(b * C_INCH + c) * T_N + t) << 14) + (size_t)h * W_IMG + w;
    out[oidx] = tmp[row * KPATCH + kk] + ub[c] + xin[oidx];
}

// ---------------------------------------------------------------
extern "C" void kernel_launch(void* const* d_in, const int* in_sizes, int n_in,
                              void* d_out, int out_size, void* d_ws, size_t ws_size,
                              hipStream_t stream) {
    const float* x       = (const float*)d_in[0];
    const float* patch_w = (const float*)d_in[1];
    const float* patch_b = (const float*)d_in[2];
    const float* W_in    = (const float*)d_in[3];
    const float* conv_w  = (const float*)d_in[4];
    const float* conv_b  = (const float*)d_in[5];
    const float* dt_bias = (const float*)d_in[6];
    const float* A_log   = (const float*)d_in[7];
    const float* D_param = (const float*)d_in[8];
    const float* norm_w  = (const float*)d_in[9];
    const float* W_out   = (const float*)d_in[10];
    const float* unemb_w = (const float*)d_in[11];
    const float* unemb_b = (const float*)d_in[12];
    float* out = (float*)d_out;

    // ---- workspace carve (bytes) ----
    char* p = (char*)d_ws;
    float* zx   = (float*)p;   p += (size_t)BLROWS * D_PROJ * 4;      // 139.5 MB (z | xBC->y | dt)
    float* dtv  = (float*)p;   p += (size_t)BLROWS * 8 * 4;
    float* dAv  = (float*)p;   p += (size_t)BLROWS * 8 * 4;
    float* cdv  = (float*)p;   p += (size_t)BLROWS * 8 * 4;
    float* sbuf = (float*)p;   p += (size_t)32 * NCH * 1024 * 4;      // 8.4 MB
    float* hin  = (float*)p;   p += (size_t)32 * NCH * 1024 * 4;      // 8.4 MB
    float* wtp  = (float*)p;   p += (size_t)KPATCH * DM_ * 4;
    float* wtu  = (float*)p;   p += (size_t)KPATCH * DM_ * 4;         // (unused now, kept for layout stability)
    ushort_t* xs  = (ushort_t*)p; p += (size_t)BLROWS * DM_ * 2;      // 16.8 MB (bf16)
    ushort_t* xbc = (ushort_t*)p; p += (size_t)BLROWS * CONV_DIM_ * 2;// 35.7 MB (bf16)
    size_t need = (size_t)(p - (char*)d_ws);
    if (ws_size < need) return;   // deterministic no-op -> clean absmax fail = diagnostic

    // tmp[BL,368] for unembed GEMM result overlays zx (z cols dead after k_norm)
    float* tmp = zx;

    k_transpose<<<KPATCH, 256, 0, stream>>>(patch_w, wtp);

    k_patch<<<dim3(32, 8, 4), 256, 0, stream>>>(x, wtp, patch_b, xs);

    // in-proj: zx[BL,1064] = xs[BL,256] @ W_in
    k_gemm<256, 1064, true, false><<<dim3(5, 1024), 256, 0, stream>>>(xs, 256, 0, W_in, zx, D_PROJ, 0);

    k_conv<<<BLROWS, 256, 0, stream>>>(zx, conv_w, conv_b, dt_bias, A_log, xbc, dtv, dAv);

    k_scan_chunk<<<dim3(NCH, 8, 4), 256, 0, stream>>>(xbc, dtv, dAv, D_param, zx, cdv, sbuf);
    k_chain<<<dim3(8, 4), 256, 0, stream>>>(sbuf, cdv, hin);
    k_fixup<<<65536, 256, 0, stream>>>(xbc, cdv, hin, zx);

    k_norm<<<BLROWS, 256, 0, stream>>>(zx, norm_w);

    // out-proj: out_seq[BL,256] = y[BL,512] @ W_out ; y lives in zx cols 512..1023
    k_gemm<512, 256, false, true><<<dim3(1, 1024), 256, 0, stream>>>(zx, D_PROJ, 512, W_out, xs, DM_, 0);

    // unembed GEMM: tmp[BL,368] = out_seq[BL,256] @ unemb_w[256,368]
    k_gemm<256, 368, true, false><<<dim3(2, 1024), 256, 0, stream>>>(xs, 256, 0, unemb_w, tmp, KPATCH, 0);

    // scatter + bias + residual
    k_scatter<<<dim3(64, 184, 4), 256, 0, stream>>>(tmp, unemb_b, x, out);
}

// Round 4
// 464.417 us; speedup vs baseline: 4.7001x; 2.2090x over previous
//
#include <hip/hip_runtime.h>
#include <hip/hip_bf16.h>
#include <cstdint>
#include <cstddef>

// ---- problem constants ----
#define B_N       4
#define C_INCH    23
#define T_N       8
#define W_IMG     128
#define L_SEQ     8192
#define BLROWS    32768      // B_N * L_SEQ
#define DM_       256
#define D_INNER_  512
#define CONV_DIM_ 544
#define D_PROJ    1064
#define KPATCH    368        // C_INCH*4*4
#define QCH       128        // scan chunk length
#define NCH       64         // chunks per batch

typedef unsigned short ushort_t;
typedef unsigned int uint_t;
typedef __attribute__((ext_vector_type(8))) short short8;
typedef __attribute__((ext_vector_type(4))) float f32x4;

__device__ __forceinline__ float b2f(ushort_t u) {
    union { float f; uint_t u; } v; v.u = ((uint_t)u) << 16; return v.f;
}
__device__ __forceinline__ ushort_t f2b(float f) {
    union { float f; uint_t u; } v; v.f = f;
    uint_t r = v.u + 0x7fffu + ((v.u >> 16) & 1u);
    return (ushort_t)(r >> 16);
}
__device__ __forceinline__ float2 bpair(uint_t u) {
    union { float f; uint_t u; } a, b;
    a.u = u << 16; b.u = u & 0xffff0000u;
    return make_float2(a.f, b.f);
}

// async global->LDS, 16B per lane. LDS dest = wave-uniform base + lane*16.
__device__ __forceinline__ void gload_lds16(const ushort_t* g, ushort_t* l) {
    __builtin_amdgcn_global_load_lds(
        (const __attribute__((address_space(1))) unsigned int*)g,
        (__attribute__((address_space(3))) unsigned int*)l, 16, 0, 0);
}

// ---------------------------------------------------------------
// weight prep: dst[Npad][K] bf16 = transpose(src[K][N] fp32); rows n>=N zeroed.
__global__ void k_transcast(const float* __restrict__ src, ushort_t* __restrict__ dst,
                            int K, int N) {
    int n = blockIdx.x;
    for (int k = threadIdx.x; k < K; k += 256)
        dst[(size_t)n * K + k] = (n < N) ? f2b(src[(size_t)k * N + n]) : (ushort_t)0;
}

// patch weights are already [d][k]: direct cast + pad k to 384
__global__ void k_castpad(const float* __restrict__ src, ushort_t* __restrict__ dst) {
    int d = blockIdx.x; int k = threadIdx.x;   // 384 threads
    dst[d * 384 + k] = (k < KPATCH) ? f2b(src[d * KPATCH + k]) : (ushort_t)0;
}

// xs += patch bias (bf16 in-place)
__global__ void __launch_bounds__(256) k_bias(ushort_t* __restrict__ xsb,
                                              const float* __restrict__ pb) {
    size_t i = (size_t)blockIdx.x * 256 + threadIdx.x;   // over BLROWS*256
    int d = (int)(i & 255);
    xsb[i] = f2b(b2f(xsb[i]) + pb[d]);
}

// ---------------------------------------------------------------
// im2col gather: Aim[row][384] bf16, row=(b,t,hp,wp), kk=c*16+i*4+j; kk>=368 -> 0
__global__ void __launch_bounds__(256) k_im2col(const float* __restrict__ x,
                                                ushort_t* __restrict__ Aim) {
    int hp = blockIdx.x, t = blockIdx.y, b = blockIdx.z;
    int tid = threadIdx.x;
    int half = tid >> 7, q = tid & 127;
    int wp = q >> 2, j = q & 3;
    size_t rowbase = (size_t)b * L_SEQ + t * 1024 + hp * 32;
    #pragma unroll
    for (int it = 0; it < 2; ++it) {
        int idx = it * 256 + tid;
        int wpz = idx >> 4, kz = KPATCH + (idx & 15);
        Aim[(rowbase + wpz) * 384 + kz] = 0;
    }
    for (int s2 = 0; s2 < 46; ++s2) {
        int seg = s2 * 2 + half;            // c*4+i
        int c = seg >> 2, i = seg & 3;
        float v = x[(((size_t)(b * C_INCH + c) * T_N + t) << 14) + (size_t)(hp * 4 + i) * W_IMG + q];
        Aim[(rowbase + wp) * 384 + c * 16 + i * 4 + j] = f2b(v);
    }
}

// ---------------------------------------------------------------
// MFMA GEMM: C[M,N] = A[M,K](bf16) @ Wt[n][k](bf16, padded rows). 128x128 tile,
// 4 waves (2x2 of 64x64), BK=64, global_load_lds staging, XOR-swizzled LDS.
template <int K, int N, bool CBF>
__global__ void __launch_bounds__(256) k_mgemm(const ushort_t* __restrict__ A, const int lda,
                                               const ushort_t* __restrict__ Wt,
                                               void* __restrict__ Cv, const int ldc, const int coff) {
    __shared__ ushort_t Al[128 * 64];
    __shared__ ushort_t Bl[128 * 64];
    const int tid = threadIdx.x;
    const int w = tid >> 6, lane = tid & 63;
    const int wr = w >> 1, wc = w & 1;
    const int rowbase = blockIdx.y * 128;
    const int colbase = blockIdx.x * 128;
    const int g = lane >> 4, r = lane & 15;

    f32x4 acc[4][4];
    #pragma unroll
    for (int i = 0; i < 4; ++i)
        #pragma unroll
        for (int j = 0; j < 4; ++j) acc[i][j] = (f32x4){0.f, 0.f, 0.f, 0.f};

    for (int k0 = 0; k0 < K; k0 += 64) {
        __syncthreads();
        #pragma unroll
        for (int it = 0; it < 4; ++it) {
            int s = it * 256 + (w << 6) + lane;
            int row = s >> 3;
            int c16 = (s & 7) ^ (row & 7);
            gload_lds16(A + (size_t)(rowbase + row) * lda + k0 + c16 * 8,
                        &Al[(size_t)(it * 256 + (w << 6)) * 8]);
        }
        #pragma unroll
        for (int it = 0; it < 4; ++it) {
            int s = it * 256 + (w << 6) + lane;
            int row = s >> 3;
            int c16 = (s & 7) ^ (row & 7);
            gload_lds16(Wt + (size_t)(colbase + row) * K + k0 + c16 * 8,
                        &Bl[(size_t)(it * 256 + (w << 6)) * 8]);
        }
        __syncthreads();

        short8 af[2][4], bf[2][4];
        #pragma unroll
        for (int ks = 0; ks < 2; ++ks)
            #pragma unroll
            for (int mi = 0; mi < 4; ++mi) {
                int row = (wr << 6) + (mi << 4) + r;
                int c16 = ((ks << 2) | g) ^ (row & 7);
                af[ks][mi] = *(const short8*)&Al[(size_t)((row << 3) + c16) * 8];
            }
        #pragma unroll
        for (int ks = 0; ks < 2; ++ks)
            #pragma unroll
            for (int ni = 0; ni < 4; ++ni) {
                int row = (wc << 6) + (ni << 4) + r;
                int c16 = ((ks << 2) | g) ^ (row & 7);
                bf[ks][ni] = *(const short8*)&Bl[(size_t)((row << 3) + c16) * 8];
            }
        #pragma unroll
        for (int ks = 0; ks < 2; ++ks)
            #pragma unroll
            for (int mi = 0; mi < 4; ++mi)
                #pragma unroll
                for (int ni = 0; ni < 4; ++ni)
                    acc[mi][ni] = __builtin_amdgcn_mfma_f32_16x16x32_bf16(
                        af[ks][mi], bf[ks][ni], acc[mi][ni], 0, 0, 0);
    }

    // C store: D col=lane&15, row=(lane>>4)*4+reg
    #pragma unroll
    for (int mi = 0; mi < 4; ++mi) {
        #pragma unroll
        for (int ni = 0; ni < 4; ++ni) {
            int col = colbase + (wc << 6) + (ni << 4) + r;
            if (col < N) {
                int rw = rowbase + (wr << 6) + (mi << 4) + (g << 2);
                f32x4 v = acc[mi][ni];
                #pragma unroll
                for (int j = 0; j < 4; ++j) {
                    size_t cidx = (size_t)(rw + j) * ldc + coff + col;
                    if (CBF) ((ushort_t*)Cv)[cidx] = f2b(v[j]);
                    else     ((float*)Cv)[cidx]   = v[j];
                }
            }
        }
    }
}

// ---------------------------------------------------------------
// causal depthwise conv (kernel 4) + silu -> xbc (bf16), plus dt softplus/dA.
__global__ void __launch_bounds__(256) k_conv(const float* __restrict__ zx,
                                              const float* __restrict__ cw,
                                              const float* __restrict__ cb,
                                              const float* __restrict__ dtb,
                                              const float* __restrict__ alog,
                                              ushort_t* __restrict__ xbc,
                                              float* __restrict__ dtv,
                                              float* __restrict__ dAv) {
    int row = blockIdx.x;
    int l = row & (L_SEQ - 1);
    for (int ch = threadIdx.x; ch < 552; ch += 256) {
        if (ch < CONV_DIM_) {
            float acc = cb[ch];
            #pragma unroll
            for (int k = 0; k < 4; ++k) {
                int lo = l + k - 3;
                if (lo >= 0) {
                    acc += zx[(size_t)(row + k - 3) * D_PROJ + D_INNER_ + ch] * cw[ch * 4 + k];
                }
            }
            float s = acc / (1.f + __expf(-acc));
            xbc[(size_t)row * CONV_DIM_ + ch] = f2b(s);
        } else {
            int h = ch - CONV_DIM_;
            float v = zx[(size_t)row * D_PROJ + (D_INNER_ + CONV_DIM_) + h] + dtb[h];
            float sp = (v > 20.f) ? v : log1pf(__expf(v));
            float A = -__expf(alog[h]);
            dtv[row * 8 + h] = sp;
            dAv[row * 8 + h] = __expf(sp * A);
        }
    }
}

// ---------------------------------------------------------------
__global__ void __launch_bounds__(256) k_scan_chunk(const ushort_t* __restrict__ xbc,
                                                    const float* __restrict__ dtv,
                                                    const float* __restrict__ dAv,
                                                    const float* __restrict__ Dp,
                                                    float* __restrict__ zx,
                                                    float* __restrict__ cdv,
                                                    float* __restrict__ sbuf) {
    int c = blockIdx.x, h = blockIdx.y, b = blockIdx.z;
    int tid = threadIdx.x;
    int p = tid >> 2, nq = tid & 3;
    float h0 = 0.f, h1 = 0.f, h2 = 0.f, h3 = 0.f;
    float cd = 1.f;
    float Dh = Dp[h];
    size_t row0 = (size_t)b * L_SEQ + (size_t)c * QCH;
    for (int s = 0; s < QCH; ++s) {
        size_t row = row0 + s;
        float da  = dAv[row * 8 + h];
        float dtt = dtv[row * 8 + h];
        float xh  = b2f(xbc[row * CONV_DIM_ + h * 64 + p]);
        const uint_t* bc = (const uint_t*)(xbc + row * CONV_DIM_ + 512);
        float2 Bl = bpair(bc[nq * 2 + 0]);
        float2 Bh = bpair(bc[nq * 2 + 1]);
        float2 Cl = bpair(bc[8 + nq * 2 + 0]);
        float2 Ch = bpair(bc[8 + nq * 2 + 1]);
        float xdt = xh * dtt;
        h0 = da * h0 + xdt * Bl.x;
        h1 = da * h1 + xdt * Bl.y;
        h2 = da * h2 + xdt * Bh.x;
        h3 = da * h3 + xdt * Bh.y;
        float part = h0 * Cl.x + h1 * Cl.y + h2 * Ch.x + h3 * Ch.y;
        part += __shfl_xor(part, 1);
        part += __shfl_xor(part, 2);
        cd *= da;
        if (nq == 0) zx[row * D_PROJ + 512 + h * 64 + p] = part + Dh * xh;
        if (tid == 0) cdv[row * 8 + h] = cd;
    }
    float4 st = make_float4(h0, h1, h2, h3);
    *(float4*)&sbuf[(((size_t)(b * 8 + h) * NCH + c) << 10) + tid * 4] = st;
}

// ---------------------------------------------------------------
__global__ void __launch_bounds__(256) k_chain(const float* __restrict__ sbuf,
                                               const float* __restrict__ cdv,
                                               float* __restrict__ hin) {
    int h = blockIdx.x, b = blockIdx.y;
    int tid = threadIdx.x;
    float4 H = make_float4(0.f, 0.f, 0.f, 0.f);
    size_t base = ((size_t)(b * 8 + h) * NCH) << 10;
    for (int c = 0; c < NCH; ++c) {
        *(float4*)&hin[base + ((size_t)c << 10) + tid * 4] = H;
        float cdf = cdv[((size_t)b * L_SEQ + (size_t)c * QCH + (QCH - 1)) * 8 + h];
        float4 S = *(const float4*)&sbuf[base + ((size_t)c << 10) + tid * 4];
        H.x = cdf * H.x + S.x;
        H.y = cdf * H.y + S.y;
        H.z = cdf * H.z + S.z;
        H.w = cdf * H.w + S.w;
    }
}

// ---------------------------------------------------------------
__global__ void __launch_bounds__(256) k_fixup(const ushort_t* __restrict__ xbc,
                                               const float* __restrict__ cdv,
                                               const float* __restrict__ hin,
                                               float* __restrict__ zx) {
    size_t g = (size_t)blockIdx.x * 256 + threadIdx.x;
    int p = (int)(g & 63);
    int h = (int)((g >> 6) & 7);
    size_t row = g >> 9;
    int b = (int)(row >> 13);
    int l = (int)(row & (L_SEQ - 1));
    int c = l >> 7;
    float cd = cdv[row * 8 + h];
    const float* Hrow = &hin[(((size_t)(b * 8 + h) * NCH + c) << 10) + p * 16];
    const uint_t* Cp = (const uint_t*)(xbc + row * CONV_DIM_ + 528);
    float dot = 0.f;
    #pragma unroll
    for (int n4 = 0; n4 < 4; ++n4) {
        float4 Hv = *(const float4*)&Hrow[n4 * 4];
        float2 c0 = bpair(Cp[n4 * 2 + 0]);
        float2 c1 = bpair(Cp[n4 * 2 + 1]);
        dot += Hv.x * c0.x + Hv.y * c0.y + Hv.z * c1.x + Hv.w * c1.y;
    }
    zx[row * D_PROJ + 512 + (int)(g & 511)] += cd * dot;
}

// ---------------------------------------------------------------
__global__ void __launch_bounds__(256) k_norm(const float* __restrict__ zx,
                                              const float* __restrict__ nw,
                                              ushort_t* __restrict__ yn) {
    int row = blockIdx.x;
    int tid = threadIdx.x;
    size_t rb = (size_t)row * D_PROJ;
    float yv0 = zx[rb + 512 + tid];
    float yv1 = zx[rb + 768 + tid];
    float z0 = zx[rb + tid];
    float z1 = zx[rb + 256 + tid];
    float yg0 = yv0 * (z0 / (1.f + __expf(-z0)));
    float yg1 = yv1 * (z1 / (1.f + __expf(-z1)));
    float sq = yg0 * yg0 + yg1 * yg1;
    #pragma unroll
    for (int off = 32; off >= 1; off >>= 1) sq += __shfl_xor(sq, off);
    __shared__ float wsum[4];
    int wid = tid >> 6;
    if ((tid & 63) == 0) wsum[wid] = sq;
    __syncthreads();
    float tot = wsum[0] + wsum[1] + wsum[2] + wsum[3];
    float scale = rsqrtf(tot * (1.f / 512.f) + 1e-5f);
    yn[(size_t)row * 512 + tid]       = f2b(yg0 * scale * nw[tid]);
    yn[(size_t)row * 512 + 256 + tid] = f2b(yg1 * scale * nw[256 + tid]);
}

// ---------------------------------------------------------------
__global__ void __launch_bounds__(256) k_scatter(const float* __restrict__ tmp,
                                                 const float* __restrict__ ub,
                                                 const float* __restrict__ xin,
                                                 float* __restrict__ out) {
    int tid = threadIdx.x;
    int w = tid & 127;
    int h = (blockIdx.x << 1) | (tid >> 7);
    int c = blockIdx.y >> 3, t = blockIdx.y & 7;
    int b = blockIdx.z;
    size_t row = (size_t)b * L_SEQ + t * 1024 + (h >> 2) * 32 + (w >> 2);
    int kk = c * 16 + (h & 3) * 4 + (w & 3);
    size_t oidx = (((size_t)(b * C_INCH + c) * T_N + t) << 14) + (size_t)h * W_IMG + w;
    out[oidx] = tmp[row * KPATCH + kk] + ub[c] + xin[oidx];
}

// ---------------------------------------------------------------
extern "C" void kernel_launch(void* const* d_in, const int* in_sizes, int n_in,
                              void* d_out, int out_size, void* d_ws, size_t ws_size,
                              hipStream_t stream) {
    const float* x       = (const float*)d_in[0];
    const float* patch_w = (const float*)d_in[1];
    const float* patch_b = (const float*)d_in[2];
    const float* W_in    = (const float*)d_in[3];
    const float* conv_w  = (const float*)d_in[4];
    const float* conv_b  = (const float*)d_in[5];
    const float* dt_bias = (const float*)d_in[6];
    const float* A_log   = (const float*)d_in[7];
    const float* D_param = (const float*)d_in[8];
    const float* norm_w  = (const float*)d_in[9];
    const float* W_out   = (const float*)d_in[10];
    const float* unemb_w = (const float*)d_in[11];
    const float* unemb_b = (const float*)d_in[12];
    float* out = (float*)d_out;

    // ---- workspace carve ----
    char* p = (char*)d_ws;
    float* zx   = (float*)p;   p += (size_t)BLROWS * D_PROJ * 4;
    float* dtv  = (float*)p;   p += (size_t)BLROWS * 8 * 4;
    float* dAv  = (float*)p;   p += (size_t)BLROWS * 8 * 4;
    float* cdv  = (float*)p;   p += (size_t)BLROWS * 8 * 4;
    float* sbuf = (float*)p;   p += (size_t)32 * NCH * 1024 * 4;
    float* hin  = (float*)p;   p += (size_t)32 * NCH * 1024 * 4;
    ushort_t* Wt_p   = (ushort_t*)p; p += (size_t)256 * 384 * 2;
    ushort_t* Wt_in  = (ushort_t*)p; p += (size_t)1152 * 256 * 2;
    ushort_t* Wt_out = (ushort_t*)p; p += (size_t)256 * 512 * 2;
    ushort_t* Wt_un  = (ushort_t*)p; p += (size_t)384 * 256 * 2;
    ushort_t* xs  = (ushort_t*)p; p += (size_t)BLROWS * DM_ * 2;
    ushort_t* xbc = (ushort_t*)p; p += (size_t)BLROWS * CONV_DIM_ * 2;
    size_t need = (size_t)(p - (char*)d_ws);
    if (ws_size < need) return;

    ushort_t* Aim   = (ushort_t*)zx;   // im2col overlays zx (dead until in-proj output)
    ushort_t* ynorm = xbc;             // overlays xbc (dead after k_fixup)
    float* tmp      = zx;              // unembed output overlays zx (dead after k_norm)

    k_castpad<<<256, 384, 0, stream>>>(patch_w, Wt_p);
    k_transcast<<<1152, 256, 0, stream>>>(W_in, Wt_in, 256, 1064);
    k_transcast<<<256, 256, 0, stream>>>(W_out, Wt_out, 512, 256);
    k_transcast<<<384, 256, 0, stream>>>(unemb_w, Wt_un, 256, 368);

    k_im2col<<<dim3(32, 8, 4), 256, 0, stream>>>(x, Aim);
    k_mgemm<384, 256, true><<<dim3(2, 256), 256, 0, stream>>>(Aim, 384, Wt_p, xs, 256, 0);
    k_bias<<<BLROWS, 256, 0, stream>>>(xs, patch_b);

    k_mgemm<256, 1064, false><<<dim3(9, 256), 256, 0, stream>>>(xs, 256, Wt_in, zx, D_PROJ, 0);

    k_conv<<<BLROWS, 256, 0, stream>>>(zx, conv_w, conv_b, dt_bias, A_log, xbc, dtv, dAv);

    k_scan_chunk<<<dim3(NCH, 8, 4), 256, 0, stream>>>(xbc, dtv, dAv, D_param, zx, cdv, sbuf);
    k_chain<<<dim3(8, 4), 256, 0, stream>>>(sbuf, cdv, hin);
    k_fixup<<<65536, 256, 0, stream>>>(xbc, cdv, hin, zx);

    k_norm<<<BLROWS, 256, 0, stream>>>(zx, norm_w, ynorm);

    k_mgemm<512, 256, true><<<dim3(2, 256), 256, 0, stream>>>(ynorm, 512, Wt_out, xs, DM_, 0);

    k_mgemm<256, 368, false><<<dim3(3, 256), 256, 0, stream>>>(xs, 256, Wt_un, tmp, KPATCH, 0);

    k_scatter<<<dim3(64, 184, 4), 256, 0, stream>>>(tmp, unemb_b, x, out);
}

// Round 5
// 408.938 us; speedup vs baseline: 5.3377x; 1.1357x over previous
//
#include <hip/hip_runtime.h>
#include <hip/hip_bf16.h>
#include <cstdint>
#include <cstddef>

// ---- problem constants ----
#define B_N       4
#define C_INCH    23
#define T_N       8
#define W_IMG     128
#define L_SEQ     8192
#define BLROWS    32768      // B_N * L_SEQ
#define DM_       256
#define D_INNER_  512
#define CONV_DIM_ 544
#define D_PROJ    1064
#define KPATCH    368        // C_INCH*4*4
#define QCH       128        // scan chunk length
#define NCH       64         // chunks per batch

typedef unsigned short ushort_t;
typedef unsigned int uint_t;
typedef __attribute__((ext_vector_type(8))) short short8;
typedef __attribute__((ext_vector_type(4))) float f32x4;

__device__ __forceinline__ float b2f(ushort_t u) {
    union { float f; uint_t u; } v; v.u = ((uint_t)u) << 16; return v.f;
}
__device__ __forceinline__ ushort_t f2b(float f) {
    union { float f; uint_t u; } v; v.f = f;
    uint_t r = v.u + 0x7fffu + ((v.u >> 16) & 1u);
    return (ushort_t)(r >> 16);
}

// async global->LDS, 16B per lane. LDS dest = wave-uniform base + lane*16.
__device__ __forceinline__ void gload_lds16(const ushort_t* g, ushort_t* l) {
    __builtin_amdgcn_global_load_lds(
        (const __attribute__((address_space(1))) unsigned int*)g,
        (__attribute__((address_space(3))) unsigned int*)l, 16, 0, 0);
}

// ---------------------------------------------------------------
// weight prep: dst[Npad][K] bf16 = transpose(src[K][N] fp32); rows n>=N zeroed.
__global__ void k_transcast(const float* __restrict__ src, ushort_t* __restrict__ dst,
                            int K, int N) {
    int n = blockIdx.x;
    for (int k = threadIdx.x; k < K; k += 256)
        dst[(size_t)n * K + k] = (n < N) ? f2b(src[(size_t)k * N + n]) : (ushort_t)0;
}

// patch weights are already [d][k]: direct cast + pad k to 384
__global__ void k_castpad(const float* __restrict__ src, ushort_t* __restrict__ dst) {
    int d = blockIdx.x; int k = threadIdx.x;   // 384 threads
    dst[d * 384 + k] = (k < KPATCH) ? f2b(src[d * KPATCH + k]) : (ushort_t)0;
}

// ---------------------------------------------------------------
// im2col gather: Aim[row][384] bf16, row=(b,t,hp,wp), kk=c*16+i*4+j; kk>=368 -> 0
__global__ void __launch_bounds__(256) k_im2col(const float* __restrict__ x,
                                                ushort_t* __restrict__ Aim) {
    int hp = blockIdx.x, t = blockIdx.y, b = blockIdx.z;
    int tid = threadIdx.x;
    int half = tid >> 7, q = tid & 127;
    int wp = q >> 2, j = q & 3;
    size_t rowbase = (size_t)b * L_SEQ + t * 1024 + hp * 32;
    #pragma unroll
    for (int it = 0; it < 2; ++it) {
        int idx = it * 256 + tid;
        int wpz = idx >> 4, kz = KPATCH + (idx & 15);
        Aim[(rowbase + wpz) * 384 + kz] = 0;
    }
    for (int s2 = 0; s2 < 46; ++s2) {
        int seg = s2 * 2 + half;            // c*4+i
        int c = seg >> 2, i = seg & 3;
        float v = x[(((size_t)(b * C_INCH + c) * T_N + t) << 14) + (size_t)(hp * 4 + i) * W_IMG + q];
        Aim[(rowbase + wp) * 384 + c * 16 + i * 4 + j] = f2b(v);
    }
}

// ---------------------------------------------------------------
// MFMA GEMM: C[M,N] = A[M,K](bf16) @ Wt[n][k](bf16, padded rows) [+ bias[n]].
// 128x128 tile, 4 waves (2x2 of 64x64), BK=64, global_load_lds staging,
// XOR-swizzled LDS.
template <int K, int N, bool CBF>
__global__ void __launch_bounds__(256) k_mgemm(const ushort_t* __restrict__ A, const int lda,
                                               const ushort_t* __restrict__ Wt,
                                               void* __restrict__ Cv, const int ldc, const int coff,
                                               const float* __restrict__ bias) {
    __shared__ ushort_t Al[128 * 64];
    __shared__ ushort_t Bl[128 * 64];
    const int tid = threadIdx.x;
    const int w = tid >> 6, lane = tid & 63;
    const int wr = w >> 1, wc = w & 1;
    const int rowbase = blockIdx.y * 128;
    const int colbase = blockIdx.x * 128;
    const int g = lane >> 4, r = lane & 15;

    f32x4 acc[4][4];
    #pragma unroll
    for (int i = 0; i < 4; ++i)
        #pragma unroll
        for (int j = 0; j < 4; ++j) acc[i][j] = (f32x4){0.f, 0.f, 0.f, 0.f};

    for (int k0 = 0; k0 < K; k0 += 64) {
        __syncthreads();
        #pragma unroll
        for (int it = 0; it < 4; ++it) {
            int s = it * 256 + (w << 6) + lane;
            int row = s >> 3;
            int c16 = (s & 7) ^ (row & 7);
            gload_lds16(A + (size_t)(rowbase + row) * lda + k0 + c16 * 8,
                        &Al[(size_t)(it * 256 + (w << 6)) * 8]);
        }
        #pragma unroll
        for (int it = 0; it < 4; ++it) {
            int s = it * 256 + (w << 6) + lane;
            int row = s >> 3;
            int c16 = (s & 7) ^ (row & 7);
            gload_lds16(Wt + (size_t)(colbase + row) * K + k0 + c16 * 8,
                        &Bl[(size_t)(it * 256 + (w << 6)) * 8]);
        }
        __syncthreads();

        short8 af[2][4], bf[2][4];
        #pragma unroll
        for (int ks = 0; ks < 2; ++ks)
            #pragma unroll
            for (int mi = 0; mi < 4; ++mi) {
                int row = (wr << 6) + (mi << 4) + r;
                int c16 = ((ks << 2) | g) ^ (row & 7);
                af[ks][mi] = *(const short8*)&Al[(size_t)((row << 3) + c16) * 8];
            }
        #pragma unroll
        for (int ks = 0; ks < 2; ++ks)
            #pragma unroll
            for (int ni = 0; ni < 4; ++ni) {
                int row = (wc << 6) + (ni << 4) + r;
                int c16 = ((ks << 2) | g) ^ (row & 7);
                bf[ks][ni] = *(const short8*)&Bl[(size_t)((row << 3) + c16) * 8];
            }
        #pragma unroll
        for (int ks = 0; ks < 2; ++ks)
            #pragma unroll
            for (int mi = 0; mi < 4; ++mi)
                #pragma unroll
                for (int ni = 0; ni < 4; ++ni)
                    acc[mi][ni] = __builtin_amdgcn_mfma_f32_16x16x32_bf16(
                        af[ks][mi], bf[ks][ni], acc[mi][ni], 0, 0, 0);
    }

    // C store: D col=lane&15, row=(lane>>4)*4+reg
    #pragma unroll
    for (int mi = 0; mi < 4; ++mi) {
        #pragma unroll
        for (int ni = 0; ni < 4; ++ni) {
            int col = colbase + (wc << 6) + (ni << 4) + r;
            if (col < N) {
                float bv = bias ? bias[col] : 0.f;
                int rw = rowbase + (wr << 6) + (mi << 4) + (g << 2);
                f32x4 v = acc[mi][ni];
                #pragma unroll
                for (int j = 0; j < 4; ++j) {
                    size_t cidx = (size_t)(rw + j) * ldc + coff + col;
                    if (CBF) ((ushort_t*)Cv)[cidx] = f2b(v[j] + bv);
                    else     ((float*)Cv)[cidx]   = v[j] + bv;
                }
            }
        }
    }
}

// ---------------------------------------------------------------
// causal depthwise conv (kernel 4) + silu. Channels 0..511 -> xbc (bf16, stride 512);
// channels 512..543 (B,C) -> bc32 fp32; dt -> softplus/dA.
__global__ void __launch_bounds__(256) k_conv(const float* __restrict__ zx,
                                              const float* __restrict__ cw,
                                              const float* __restrict__ cb,
                                              const float* __restrict__ dtb,
                                              const float* __restrict__ alog,
                                              ushort_t* __restrict__ xbc,
                                              float* __restrict__ bc32,
                                              float* __restrict__ dtv,
                                              float* __restrict__ dAv) {
    int row = blockIdx.x;
    int l = row & (L_SEQ - 1);
    for (int ch = threadIdx.x; ch < 552; ch += 256) {
        if (ch < CONV_DIM_) {
            float acc = cb[ch];
            #pragma unroll
            for (int k = 0; k < 4; ++k) {
                int lo = l + k - 3;
                if (lo >= 0) {
                    acc += zx[(size_t)(row + k - 3) * D_PROJ + D_INNER_ + ch] * cw[ch * 4 + k];
                }
            }
            float s = acc / (1.f + __expf(-acc));
            if (ch < 512) xbc[(size_t)row * 512 + ch] = f2b(s);
            else          bc32[(size_t)row * 32 + (ch - 512)] = s;
        } else {
            int h = ch - CONV_DIM_;
            float v = zx[(size_t)row * D_PROJ + (D_INNER_ + CONV_DIM_) + h] + dtb[h];
            float sp = (v > 20.f) ? v : log1pf(__expf(v));
            float A = -__expf(alog[h]);
            dtv[row * 8 + h] = sp;
            dAv[row * 8 + h] = __expf(sp * A);
        }
    }
}

// ---------------------------------------------------------------
// chunked scan phase 1. thread = one p (holds all 16 states); block = 4 heads x 64 p.
// grid (NCH, 2, B). No cross-lane ops; B/C loaded as wave-uniform fp32.
__global__ void __launch_bounds__(256) k_scan_chunk(const ushort_t* __restrict__ xbc,
                                                    const float* __restrict__ bc32,
                                                    const float* __restrict__ dtv,
                                                    const float* __restrict__ dAv,
                                                    const float* __restrict__ Dp,
                                                    float* __restrict__ zx,     // y dest cols 512..1023
                                                    float* __restrict__ cdv,
                                                    float* __restrict__ sbuf) {
    int c = blockIdx.x, b = blockIdx.z;
    int tid = threadIdx.x;
    int h = blockIdx.y * 4 + (tid >> 6);
    int p = tid & 63;
    float st[16];
    #pragma unroll
    for (int n = 0; n < 16; ++n) st[n] = 0.f;
    float cd = 1.f;
    float Dh = Dp[h];
    size_t row0 = (size_t)b * L_SEQ + (size_t)c * QCH;
    for (int s = 0; s < QCH; ++s) {
        size_t row = row0 + s;
        float da  = dAv[row * 8 + h];
        float dtt = dtv[row * 8 + h];
        float xh  = b2f(xbc[row * 512 + h * 64 + p]);
        const float4* B4 = (const float4*)(bc32 + row * 32);
        const float4* C4 = (const float4*)(bc32 + row * 32 + 16);
        float xdt = xh * dtt;
        float d0 = 0.f, d1 = 0.f, d2 = 0.f, d3 = 0.f;
        #pragma unroll
        for (int q = 0; q < 4; ++q) {
            float4 Bv = B4[q];
            float4 Cv = C4[q];
            st[q*4+0] = da * st[q*4+0] + xdt * Bv.x;
            st[q*4+1] = da * st[q*4+1] + xdt * Bv.y;
            st[q*4+2] = da * st[q*4+2] + xdt * Bv.z;
            st[q*4+3] = da * st[q*4+3] + xdt * Bv.w;
            d0 += st[q*4+0] * Cv.x;
            d1 += st[q*4+1] * Cv.y;
            d2 += st[q*4+2] * Cv.z;
            d3 += st[q*4+3] * Cv.w;
        }
        cd *= da;
        zx[row * D_PROJ + 512 + h * 64 + p] = (d0 + d1) + (d2 + d3) + Dh * xh;
        if (p == 0) cdv[row * 8 + h] = cd;
    }
    size_t base = (((size_t)(b * 8 + h) * NCH + c) << 10) + p * 16;
    #pragma unroll
    for (int q = 0; q < 4; ++q)
        *(float4*)&sbuf[base + q * 4] = make_float4(st[q*4], st[q*4+1], st[q*4+2], st[q*4+3]);
}

// ---------------------------------------------------------------
// phase 2: sequential chain over chunks (tiny). block = (h, b); thread holds 4 states.
__global__ void __launch_bounds__(256) k_chain(const float* __restrict__ sbuf,
                                               const float* __restrict__ cdv,
                                               float* __restrict__ hin) {
    int h = blockIdx.x, b = blockIdx.y;
    int tid = threadIdx.x;
    float4 H = make_float4(0.f, 0.f, 0.f, 0.f);
    size_t base = ((size_t)(b * 8 + h) * NCH) << 10;
    for (int c = 0; c < NCH; ++c) {
        *(float4*)&hin[base + ((size_t)c << 10) + tid * 4] = H;
        float cdf = cdv[((size_t)b * L_SEQ + (size_t)c * QCH + (QCH - 1)) * 8 + h];
        float4 S = *(const float4*)&sbuf[base + ((size_t)c << 10) + tid * 4];
        H.x = cdf * H.x + S.x;
        H.y = cdf * H.y + S.y;
        H.z = cdf * H.z + S.z;
        H.w = cdf * H.w + S.w;
    }
}

// ---------------------------------------------------------------
// fused fixup + gate + RMSNorm: y = ylocal + cd*(C . Hin); yg = y*silu(z);
// yn = yg * rsqrt(mean(yg^2)+eps) * nw.  block = one row.
__global__ void __launch_bounds__(256) k_fixnorm(const float* __restrict__ zx,
                                                 const float* __restrict__ bc32,
                                                 const float* __restrict__ cdv,
                                                 const float* __restrict__ hin,
                                                 const float* __restrict__ nw,
                                                 ushort_t* __restrict__ yn) {
    int row = blockIdx.x;
    int tid = threadIdx.x;
    int b = row >> 13;
    int l = row & (L_SEQ - 1);
    int c = l >> 7;                 // QCH=128
    int h0 = tid >> 6, p = tid & 63;
    int h1 = h0 + 4;
    size_t rb = (size_t)row * D_PROJ;
    const float4* C4 = (const float4*)(bc32 + (size_t)row * 32 + 16);
    float4 c0 = C4[0], c1 = C4[1], c2 = C4[2], c3 = C4[3];
    const float4* H0 = (const float4*)&hin[(((size_t)(b * 8 + h0) * NCH + c) << 10) + p * 16];
    const float4* H1 = (const float4*)&hin[(((size_t)(b * 8 + h1) * NCH + c) << 10) + p * 16];
    float4 a0, a1;
    float dot0, dot1;
    a0 = H0[0]; a1 = H0[1];
    dot0  = a0.x*c0.x + a0.y*c0.y + a0.z*c0.z + a0.w*c0.w
          + a1.x*c1.x + a1.y*c1.y + a1.z*c1.z + a1.w*c1.w;
    a0 = H0[2]; a1 = H0[3];
    dot0 += a0.x*c2.x + a0.y*c2.y + a0.z*c2.z + a0.w*c2.w
          + a1.x*c3.x + a1.y*c3.y + a1.z*c3.z + a1.w*c3.w;
    a0 = H1[0]; a1 = H1[1];
    dot1  = a0.x*c0.x + a0.y*c0.y + a0.z*c0.z + a0.w*c0.w
          + a1.x*c1.x + a1.y*c1.y + a1.z*c1.z + a1.w*c1.w;
    a0 = H1[2]; a1 = H1[3];
    dot1 += a0.x*c2.x + a0.y*c2.y + a0.z*c2.z + a0.w*c2.w
          + a1.x*c3.x + a1.y*c3.y + a1.z*c3.z + a1.w*c3.w;

    float yv0 = zx[rb + 512 + tid] + cdv[row * 8 + h0] * dot0;
    float yv1 = zx[rb + 768 + tid] + cdv[row * 8 + h1] * dot1;
    float z0 = zx[rb + tid];
    float z1 = zx[rb + 256 + tid];
    float yg0 = yv0 * (z0 / (1.f + __expf(-z0)));
    float yg1 = yv1 * (z1 / (1.f + __expf(-z1)));
    float sq = yg0 * yg0 + yg1 * yg1;
    #pragma unroll
    for (int off = 32; off >= 1; off >>= 1) sq += __shfl_xor(sq, off);
    __shared__ float wsum[4];
    int wid = tid >> 6;
    if ((tid & 63) == 0) wsum[wid] = sq;
    __syncthreads();
    float tot = wsum[0] + wsum[1] + wsum[2] + wsum[3];
    float scale = rsqrtf(tot * (1.f / 512.f) + 1e-5f);
    yn[(size_t)row * 512 + tid]       = f2b(yg0 * scale * nw[tid]);
    yn[(size_t)row * 512 + 256 + tid] = f2b(yg1 * scale * nw[256 + tid]);
}

// ---------------------------------------------------------------
__global__ void __launch_bounds__(256) k_scatter(const float* __restrict__ tmp,
                                                 const float* __restrict__ ub,
                                                 const float* __restrict__ xin,
                                                 float* __restrict__ out) {
    int tid = threadIdx.x;
    int w = tid & 127;
    int h = (blockIdx.x << 1) | (tid >> 7);
    int c = blockIdx.y >> 3, t = blockIdx.y & 7;
    int b = blockIdx.z;
    size_t row = (size_t)b * L_SEQ + t * 1024 + (h >> 2) * 32 + (w >> 2);
    int kk = c * 16 + (h & 3) * 4 + (w & 3);
    size_t oidx = (((size_t)(b * C_INCH + c) * T_N + t) << 14) + (size_t)h * W_IMG + w;
    out[oidx] = tmp[row * KPATCH + kk] + ub[c] + xin[oidx];
}

// ---------------------------------------------------------------
extern "C" void kernel_launch(void* const* d_in, const int* in_sizes, int n_in,
                              void* d_out, int out_size, void* d_ws, size_t ws_size,
                              hipStream_t stream) {
    const float* x       = (const float*)d_in[0];
    const float* patch_w = (const float*)d_in[1];
    const float* patch_b = (const float*)d_in[2];
    const float* W_in    = (const float*)d_in[3];
    const float* conv_w  = (const float*)d_in[4];
    const float* conv_b  = (const float*)d_in[5];
    const float* dt_bias = (const float*)d_in[6];
    const float* A_log   = (const float*)d_in[7];
    const float* D_param = (const float*)d_in[8];
    const float* norm_w  = (const float*)d_in[9];
    const float* W_out   = (const float*)d_in[10];
    const float* unemb_w = (const float*)d_in[11];
    const float* unemb_b = (const float*)d_in[12];
    float* out = (float*)d_out;

    // ---- workspace carve ----
    char* p = (char*)d_ws;
    float* zx   = (float*)p;   p += (size_t)BLROWS * D_PROJ * 4;
    float* dtv  = (float*)p;   p += (size_t)BLROWS * 8 * 4;
    float* dAv  = (float*)p;   p += (size_t)BLROWS * 8 * 4;
    float* cdv  = (float*)p;   p += (size_t)BLROWS * 8 * 4;
    float* sbuf = (float*)p;   p += (size_t)32 * NCH * 1024 * 4;
    float* hin  = (float*)p;   p += (size_t)32 * NCH * 1024 * 4;
    float* bc32 = (float*)p;   p += (size_t)BLROWS * 32 * 4;
    ushort_t* Wt_p   = (ushort_t*)p; p += (size_t)256 * 384 * 2;
    ushort_t* Wt_in  = (ushort_t*)p; p += (size_t)1152 * 256 * 2;
    ushort_t* Wt_out = (ushort_t*)p; p += (size_t)256 * 512 * 2;
    ushort_t* Wt_un  = (ushort_t*)p; p += (size_t)384 * 256 * 2;
    ushort_t* xs  = (ushort_t*)p; p += (size_t)BLROWS * DM_ * 2;
    ushort_t* xbc = (ushort_t*)p; p += (size_t)BLROWS * 512 * 2;
    size_t need = (size_t)(p - (char*)d_ws);
    if (ws_size < need) return;

    ushort_t* Aim   = (ushort_t*)zx;   // im2col overlays zx (dead until in-proj output)
    ushort_t* ynorm = xbc;             // overlays xbc (dead after scan)
    float* tmp      = zx;              // unembed output overlays zx (dead after fixnorm)

    k_castpad<<<256, 384, 0, stream>>>(patch_w, Wt_p);
    k_transcast<<<1152, 256, 0, stream>>>(W_in, Wt_in, 256, 1064);
    k_transcast<<<256, 256, 0, stream>>>(W_out, Wt_out, 512, 256);
    k_transcast<<<384, 256, 0, stream>>>(unemb_w, Wt_un, 256, 368);

    k_im2col<<<dim3(32, 8, 4), 256, 0, stream>>>(x, Aim);
    k_mgemm<384, 256, true><<<dim3(2, 256), 256, 0, stream>>>(Aim, 384, Wt_p, xs, 256, 0, patch_b);

    k_mgemm<256, 1064, false><<<dim3(9, 256), 256, 0, stream>>>(xs, 256, Wt_in, zx, D_PROJ, 0, nullptr);

    k_conv<<<BLROWS, 256, 0, stream>>>(zx, conv_w, conv_b, dt_bias, A_log, xbc, bc32, dtv, dAv);

    k_scan_chunk<<<dim3(NCH, 2, 4), 256, 0, stream>>>(xbc, bc32, dtv, dAv, D_param, zx, cdv, sbuf);
    k_chain<<<dim3(8, 4), 256, 0, stream>>>(sbuf, cdv, hin);

    k_fixnorm<<<BLROWS, 256, 0, stream>>>(zx, bc32, cdv, hin, norm_w, ynorm);

    k_mgemm<512, 256, true><<<dim3(2, 256), 256, 0, stream>>>(ynorm, 512, Wt_out, xs, DM_, 0, nullptr);

    k_mgemm<256, 368, false><<<dim3(3, 256), 256, 0, stream>>>(xs, 256, Wt_un, tmp, KPATCH, 0, nullptr);

    k_scatter<<<dim3(64, 184, 4), 256, 0, stream>>>(tmp, unemb_b, x, out);
}

// Round 6
// 353.735 us; speedup vs baseline: 6.1707x; 1.1561x over previous
//
#include <hip/hip_runtime.h>
#include <hip/hip_bf16.h>
#include <cstdint>
#include <cstddef>

// ---- problem constants ----
#define B_N       4
#define C_INCH    23
#define T_N       8
#define W_IMG     128
#define L_SEQ     8192
#define BLROWS    32768      // B_N * L_SEQ
#define DM_       256
#define D_INNER_  512
#define CONV_DIM_ 544
#define D_PROJ    1064
#define KPATCH    368        // C_INCH*4*4
#define QCH       128        // scan chunk length
#define NCH       64         // chunks per batch

typedef unsigned short ushort_t;
typedef unsigned int uint_t;
typedef __attribute__((ext_vector_type(8))) short short8;
typedef __attribute__((ext_vector_type(4))) float f32x4;

__device__ __forceinline__ float b2f(ushort_t u) {
    union { float f; uint_t u; } v; v.u = ((uint_t)u) << 16; return v.f;
}
__device__ __forceinline__ ushort_t f2b(float f) {
    union { float f; uint_t u; } v; v.f = f;
    uint_t r = v.u + 0x7fffu + ((v.u >> 16) & 1u);
    return (ushort_t)(r >> 16);
}

// async global->LDS, 16B per lane. LDS dest = wave-uniform base + lane*16.
__device__ __forceinline__ void gload_lds16(const ushort_t* g, ushort_t* l) {
    __builtin_amdgcn_global_load_lds(
        (const __attribute__((address_space(1))) unsigned int*)g,
        (__attribute__((address_space(3))) unsigned int*)l, 16, 0, 0);
}

// ---------------------------------------------------------------
// weight prep: dst[Npad][K] bf16 = transpose(src[K][N] fp32); rows n>=N zeroed.
__global__ void k_transcast(const float* __restrict__ src, ushort_t* __restrict__ dst,
                            int K, int N) {
    int n = blockIdx.x;
    for (int k = threadIdx.x; k < K; k += 256)
        dst[(size_t)n * K + k] = (n < N) ? f2b(src[(size_t)k * N + n]) : (ushort_t)0;
}

// patch weights are already [d][k]: direct cast + pad k to 384
__global__ void k_castpad(const float* __restrict__ src, ushort_t* __restrict__ dst) {
    int d = blockIdx.x; int k = threadIdx.x;   // 384 threads
    dst[d * 384 + k] = (k < KPATCH) ? f2b(src[d * KPATCH + k]) : (ushort_t)0;
}

// ---------------------------------------------------------------
// im2col gather: Aim[row][384] bf16, row=(b,t,hp,wp), kk=c*16+i*4+j; kk>=368 -> 0
__global__ void __launch_bounds__(256) k_im2col(const float* __restrict__ x,
                                                ushort_t* __restrict__ Aim) {
    int hp = blockIdx.x, t = blockIdx.y, b = blockIdx.z;
    int tid = threadIdx.x;
    int half = tid >> 7, q = tid & 127;
    int wp = q >> 2, j = q & 3;
    size_t rowbase = (size_t)b * L_SEQ + t * 1024 + hp * 32;
    #pragma unroll
    for (int it = 0; it < 2; ++it) {
        int idx = it * 256 + tid;
        int wpz = idx >> 4, kz = KPATCH + (idx & 15);
        Aim[(rowbase + wpz) * 384 + kz] = 0;
    }
    for (int s2 = 0; s2 < 46; ++s2) {
        int seg = s2 * 2 + half;            // c*4+i
        int c = seg >> 2, i = seg & 3;
        float v = x[(((size_t)(b * C_INCH + c) * T_N + t) << 14) + (size_t)(hp * 4 + i) * W_IMG + q];
        Aim[(rowbase + wp) * 384 + c * 16 + i * 4 + j] = f2b(v);
    }
}

// ---------------------------------------------------------------
// MFMA GEMM: C[M,N] = A[M,K](bf16) @ Wt[n][k](bf16, padded rows) [+ bias[n]].
// 128x128 tile, 4 waves (2x2 of 64x64), BK=64, global_load_lds staging,
// XOR-swizzled LDS.
template <int K, int N, bool CBF>
__global__ void __launch_bounds__(256) k_mgemm(const ushort_t* __restrict__ A, const int lda,
                                               const ushort_t* __restrict__ Wt,
                                               void* __restrict__ Cv, const int ldc, const int coff,
                                               const float* __restrict__ bias) {
    __shared__ ushort_t Al[128 * 64];
    __shared__ ushort_t Bl[128 * 64];
    const int tid = threadIdx.x;
    const int w = tid >> 6, lane = tid & 63;
    const int wr = w >> 1, wc = w & 1;
    const int rowbase = blockIdx.y * 128;
    const int colbase = blockIdx.x * 128;
    const int g = lane >> 4, r = lane & 15;

    f32x4 acc[4][4];
    #pragma unroll
    for (int i = 0; i < 4; ++i)
        #pragma unroll
        for (int j = 0; j < 4; ++j) acc[i][j] = (f32x4){0.f, 0.f, 0.f, 0.f};

    for (int k0 = 0; k0 < K; k0 += 64) {
        __syncthreads();
        #pragma unroll
        for (int it = 0; it < 4; ++it) {
            int s = it * 256 + (w << 6) + lane;
            int row = s >> 3;
            int c16 = (s & 7) ^ (row & 7);
            gload_lds16(A + (size_t)(rowbase + row) * lda + k0 + c16 * 8,
                        &Al[(size_t)(it * 256 + (w << 6)) * 8]);
        }
        #pragma unroll
        for (int it = 0; it < 4; ++it) {
            int s = it * 256 + (w << 6) + lane;
            int row = s >> 3;
            int c16 = (s & 7) ^ (row & 7);
            gload_lds16(Wt + (size_t)(colbase + row) * K + k0 + c16 * 8,
                        &Bl[(size_t)(it * 256 + (w << 6)) * 8]);
        }
        __syncthreads();

        short8 af[2][4], bf[2][4];
        #pragma unroll
        for (int ks = 0; ks < 2; ++ks)
            #pragma unroll
            for (int mi = 0; mi < 4; ++mi) {
                int row = (wr << 6) + (mi << 4) + r;
                int c16 = ((ks << 2) | g) ^ (row & 7);
                af[ks][mi] = *(const short8*)&Al[(size_t)((row << 3) + c16) * 8];
            }
        #pragma unroll
        for (int ks = 0; ks < 2; ++ks)
            #pragma unroll
            for (int ni = 0; ni < 4; ++ni) {
                int row = (wc << 6) + (ni << 4) + r;
                int c16 = ((ks << 2) | g) ^ (row & 7);
                bf[ks][ni] = *(const short8*)&Bl[(size_t)((row << 3) + c16) * 8];
            }
        #pragma unroll
        for (int ks = 0; ks < 2; ++ks)
            #pragma unroll
            for (int mi = 0; mi < 4; ++mi)
                #pragma unroll
                for (int ni = 0; ni < 4; ++ni)
                    acc[mi][ni] = __builtin_amdgcn_mfma_f32_16x16x32_bf16(
                        af[ks][mi], bf[ks][ni], acc[mi][ni], 0, 0, 0);
    }

    // C store: D col=lane&15, row=(lane>>4)*4+reg
    #pragma unroll
    for (int mi = 0; mi < 4; ++mi) {
        #pragma unroll
        for (int ni = 0; ni < 4; ++ni) {
            int col = colbase + (wc << 6) + (ni << 4) + r;
            if (col < N) {
                float bv = bias ? bias[col] : 0.f;
                int rw = rowbase + (wr << 6) + (mi << 4) + (g << 2);
                f32x4 v = acc[mi][ni];
                #pragma unroll
                for (int j = 0; j < 4; ++j) {
                    size_t cidx = (size_t)(rw + j) * ldc + coff + col;
                    if (CBF) ((ushort_t*)Cv)[cidx] = f2b(v[j] + bv);
                    else     ((float*)Cv)[cidx]   = v[j] + bv;
                }
            }
        }
    }
}

// ---------------------------------------------------------------
// causal depthwise conv (kernel 4) + silu, sliding-window over 8 rows/block.
// Input: xbcdt[BL][640] bf16 (local ch 0..543 = xBC, 544..551 = dt).
// Output: ch<512 -> xbc bf16; 512..543 -> bc32 fp32; dt -> softplus/dA.
__global__ void __launch_bounds__(256) k_conv(const ushort_t* __restrict__ xbcdt,
                                              const float* __restrict__ cw,
                                              const float* __restrict__ cb,
                                              const float* __restrict__ dtb,
                                              const float* __restrict__ alog,
                                              ushort_t* __restrict__ xbc,
                                              float* __restrict__ bc32,
                                              float* __restrict__ dtv,
                                              float* __restrict__ dAv) {
    int tid = threadIdx.x;
    int rb = blockIdx.x * 8;            // first row of this block
    int srb = rb & (L_SEQ - 1);         // seq pos within batch (blocks never straddle batches)
    #pragma unroll
    for (int it = 0; it < 3; ++it) {
        int ch = it * 256 + tid;
        if (ch >= 552) break;
        if (ch < CONV_DIM_) {
            float w0 = cw[ch * 4 + 0], w1 = cw[ch * 4 + 1];
            float w2 = cw[ch * 4 + 2], w3 = cw[ch * 4 + 3];
            float bias = cb[ch];
            float win[11];
            #pragma unroll
            for (int j = 0; j < 11; ++j) {
                int sj = srb + j - 3;
                win[j] = (sj >= 0) ? b2f(xbcdt[(size_t)(rb + j - 3) * 640 + ch]) : 0.f;
            }
            #pragma unroll
            for (int r = 0; r < 8; ++r) {
                float acc = bias + win[r] * w0 + win[r + 1] * w1 + win[r + 2] * w2 + win[r + 3] * w3;
                float s = acc / (1.f + __expf(-acc));
                size_t row = rb + r;
                if (ch < 512) xbc[row * 512 + ch] = f2b(s);
                else          bc32[row * 32 + (ch - 512)] = s;
            }
        } else {
            int h = ch - CONV_DIM_;
            float A = -__expf(alog[h]);
            float db = dtb[h];
            #pragma unroll
            for (int r = 0; r < 8; ++r) {
                size_t row = rb + r;
                float v = b2f(xbcdt[row * 640 + ch]) + db;
                float sp = (v > 20.f) ? v : log1pf(__expf(v));
                dtv[row * 8 + h] = sp;
                dAv[row * 8 + h] = __expf(sp * A);
            }
        }
    }
}

// ---------------------------------------------------------------
// chunked scan phase 1. thread = one p (holds all 16 states); block = 4 heads x 64 p.
// grid (NCH, 2, B). No cross-lane ops; B/C loaded as wave-uniform fp32.
__global__ void __launch_bounds__(256) k_scan_chunk(const ushort_t* __restrict__ xbc,
                                                    const float* __restrict__ bc32,
                                                    const float* __restrict__ dtv,
                                                    const float* __restrict__ dAv,
                                                    const float* __restrict__ Dp,
                                                    float* __restrict__ y32,
                                                    float* __restrict__ cdv,
                                                    float* __restrict__ sbuf) {
    int c = blockIdx.x, b = blockIdx.z;
    int tid = threadIdx.x;
    int h = blockIdx.y * 4 + (tid >> 6);
    int p = tid & 63;
    float st[16];
    #pragma unroll
    for (int n = 0; n < 16; ++n) st[n] = 0.f;
    float cd = 1.f;
    float Dh = Dp[h];
    size_t row0 = (size_t)b * L_SEQ + (size_t)c * QCH;
    for (int s = 0; s < QCH; ++s) {
        size_t row = row0 + s;
        float da  = dAv[row * 8 + h];
        float dtt = dtv[row * 8 + h];
        float xh  = b2f(xbc[row * 512 + h * 64 + p]);
        const float4* B4 = (const float4*)(bc32 + row * 32);
        const float4* C4 = (const float4*)(bc32 + row * 32 + 16);
        float xdt = xh * dtt;
        float d0 = 0.f, d1 = 0.f, d2 = 0.f, d3 = 0.f;
        #pragma unroll
        for (int q = 0; q < 4; ++q) {
            float4 Bv = B4[q];
            float4 Cv = C4[q];
            st[q*4+0] = da * st[q*4+0] + xdt * Bv.x;
            st[q*4+1] = da * st[q*4+1] + xdt * Bv.y;
            st[q*4+2] = da * st[q*4+2] + xdt * Bv.z;
            st[q*4+3] = da * st[q*4+3] + xdt * Bv.w;
            d0 += st[q*4+0] * Cv.x;
            d1 += st[q*4+1] * Cv.y;
            d2 += st[q*4+2] * Cv.z;
            d3 += st[q*4+3] * Cv.w;
        }
        cd *= da;
        y32[row * 512 + h * 64 + p] = (d0 + d1) + (d2 + d3) + Dh * xh;
        if (p == 0) cdv[row * 8 + h] = cd;
    }
    size_t base = (((size_t)(b * 8 + h) * NCH + c) << 10) + p * 16;
    #pragma unroll
    for (int q = 0; q < 4; ++q)
        *(float4*)&sbuf[base + q * 4] = make_float4(st[q*4], st[q*4+1], st[q*4+2], st[q*4+3]);
}

// ---------------------------------------------------------------
// phase 2: sequential chain over chunks (tiny). block = (h, b); thread holds 4 states.
__global__ void __launch_bounds__(256) k_chain(const float* __restrict__ sbuf,
                                               const float* __restrict__ cdv,
                                               float* __restrict__ hin) {
    int h = blockIdx.x, b = blockIdx.y;
    int tid = threadIdx.x;
    float4 H = make_float4(0.f, 0.f, 0.f, 0.f);
    size_t base = ((size_t)(b * 8 + h) * NCH) << 10;
    for (int c = 0; c < NCH; ++c) {
        *(float4*)&hin[base + ((size_t)c << 10) + tid * 4] = H;
        float cdf = cdv[((size_t)b * L_SEQ + (size_t)c * QCH + (QCH - 1)) * 8 + h];
        float4 S = *(const float4*)&sbuf[base + ((size_t)c << 10) + tid * 4];
        H.x = cdf * H.x + S.x;
        H.y = cdf * H.y + S.y;
        H.z = cdf * H.z + S.z;
        H.w = cdf * H.w + S.w;
    }
}

// ---------------------------------------------------------------
// fused fixup + gate + RMSNorm: y = ylocal + cd*(C . Hin); yg = y*silu(z);
// yn = yg * rsqrt(mean(yg^2)+eps) * nw.  block = one row.
__global__ void __launch_bounds__(256) k_fixnorm(const float* __restrict__ y32,
                                                 const ushort_t* __restrict__ z_bf,
                                                 const float* __restrict__ bc32,
                                                 const float* __restrict__ cdv,
                                                 const float* __restrict__ hin,
                                                 const float* __restrict__ nw,
                                                 ushort_t* __restrict__ yn) {
    int row = blockIdx.x;
    int tid = threadIdx.x;
    int b = row >> 13;
    int l = row & (L_SEQ - 1);
    int c = l >> 7;                 // QCH=128
    int h0 = tid >> 6, p = tid & 63;
    int h1 = h0 + 4;
    const float4* C4 = (const float4*)(bc32 + (size_t)row * 32 + 16);
    float4 c0 = C4[0], c1 = C4[1], c2 = C4[2], c3 = C4[3];
    const float4* H0 = (const float4*)&hin[(((size_t)(b * 8 + h0) * NCH + c) << 10) + p * 16];
    const float4* H1 = (const float4*)&hin[(((size_t)(b * 8 + h1) * NCH + c) << 10) + p * 16];
    float4 a0, a1;
    float dot0, dot1;
    a0 = H0[0]; a1 = H0[1];
    dot0  = a0.x*c0.x + a0.y*c0.y + a0.z*c0.z + a0.w*c0.w
          + a1.x*c1.x + a1.y*c1.y + a1.z*c1.z + a1.w*c1.w;
    a0 = H0[2]; a1 = H0[3];
    dot0 += a0.x*c2.x + a0.y*c2.y + a0.z*c2.z + a0.w*c2.w
          + a1.x*c3.x + a1.y*c3.y + a1.z*c3.z + a1.w*c3.w;
    a0 = H1[0]; a1 = H1[1];
    dot1  = a0.x*c0.x + a0.y*c0.y + a0.z*c0.z + a0.w*c0.w
          + a1.x*c1.x + a1.y*c1.y + a1.z*c1.z + a1.w*c1.w;
    a0 = H1[2]; a1 = H1[3];
    dot1 += a0.x*c2.x + a0.y*c2.y + a0.z*c2.z + a0.w*c2.w
          + a1.x*c3.x + a1.y*c3.y + a1.z*c3.z + a1.w*c3.w;

    size_t rb = (size_t)row * 512;
    float yv0 = y32[rb + tid]       + cdv[row * 8 + h0] * dot0;
    float yv1 = y32[rb + 256 + tid] + cdv[row * 8 + h1] * dot1;
    float z0 = b2f(z_bf[rb + tid]);
    float z1 = b2f(z_bf[rb + 256 + tid]);
    float yg0 = yv0 * (z0 / (1.f + __expf(-z0)));
    float yg1 = yv1 * (z1 / (1.f + __expf(-z1)));
    float sq = yg0 * yg0 + yg1 * yg1;
    #pragma unroll
    for (int off = 32; off >= 1; off >>= 1) sq += __shfl_xor(sq, off);
    __shared__ float wsum[4];
    int wid = tid >> 6;
    if ((tid & 63) == 0) wsum[wid] = sq;
    __syncthreads();
    float tot = wsum[0] + wsum[1] + wsum[2] + wsum[3];
    float scale = rsqrtf(tot * (1.f / 512.f) + 1e-5f);
    yn[rb + tid]       = f2b(yg0 * scale * nw[tid]);
    yn[rb + 256 + tid] = f2b(yg1 * scale * nw[256 + tid]);
}

// ---------------------------------------------------------------
__global__ void __launch_bounds__(256) k_scatter(const float* __restrict__ tmp,
                                                 const float* __restrict__ ub,
                                                 const float* __restrict__ xin,
                                                 float* __restrict__ out) {
    int tid = threadIdx.x;
    int w = tid & 127;
    int h = (blockIdx.x << 1) | (tid >> 7);
    int c = blockIdx.y >> 3, t = blockIdx.y & 7;
    int b = blockIdx.z;
    size_t row = (size_t)b * L_SEQ + t * 1024 + (h >> 2) * 32 + (w >> 2);
    int kk = c * 16 + (h & 3) * 4 + (w & 3);
    size_t oidx = (((size_t)(b * C_INCH + c) * T_N + t) << 14) + (size_t)h * W_IMG + w;
    out[oidx] = tmp[row * KPATCH + kk] + ub[c] + xin[oidx];
}

// ---------------------------------------------------------------
extern "C" void kernel_launch(void* const* d_in, const int* in_sizes, int n_in,
                              void* d_out, int out_size, void* d_ws, size_t ws_size,
                              hipStream_t stream) {
    const float* x       = (const float*)d_in[0];
    const float* patch_w = (const float*)d_in[1];
    const float* patch_b = (const float*)d_in[2];
    const float* W_in    = (const float*)d_in[3];
    const float* conv_w  = (const float*)d_in[4];
    const float* conv_b  = (const float*)d_in[5];
    const float* dt_bias = (const float*)d_in[6];
    const float* A_log   = (const float*)d_in[7];
    const float* D_param = (const float*)d_in[8];
    const float* norm_w  = (const float*)d_in[9];
    const float* W_out   = (const float*)d_in[10];
    const float* unemb_w = (const float*)d_in[11];
    const float* unemb_b = (const float*)d_in[12];
    float* out = (float*)d_out;

    // ---- workspace carve ----
    char* p = (char*)d_ws;
    float* y32  = (float*)p;   p += (size_t)BLROWS * 512 * 4;        // 67 MB (also Aim/tmp overlay)
    float* dtv  = (float*)p;   p += (size_t)BLROWS * 8 * 4;
    float* dAv  = (float*)p;   p += (size_t)BLROWS * 8 * 4;
    float* cdv  = (float*)p;   p += (size_t)BLROWS * 8 * 4;
    float* sbuf = (float*)p;   p += (size_t)32 * NCH * 1024 * 4;     // 8.4 MB
    float* hin  = (float*)p;   p += (size_t)32 * NCH * 1024 * 4;     // 8.4 MB
    float* bc32 = (float*)p;   p += (size_t)BLROWS * 32 * 4;         // 4.2 MB
    ushort_t* Wt_p   = (ushort_t*)p; p += (size_t)256 * 384 * 2;
    ushort_t* Wt_in  = (ushort_t*)p; p += (size_t)1152 * 256 * 2;
    ushort_t* Wt_out = (ushort_t*)p; p += (size_t)256 * 512 * 2;
    ushort_t* Wt_un  = (ushort_t*)p; p += (size_t)384 * 256 * 2;
    ushort_t* xs     = (ushort_t*)p; p += (size_t)BLROWS * DM_ * 2;  // 16.8 MB
    ushort_t* xbc    = (ushort_t*)p; p += (size_t)BLROWS * 512 * 2;  // 33.5 MB (reused as ynorm)
    ushort_t* z_bf   = (ushort_t*)p; p += (size_t)BLROWS * 512 * 2;  // 33.5 MB
    ushort_t* xbcdt  = (ushort_t*)p; p += (size_t)BLROWS * 640 * 2;  // 41.9 MB
    size_t need = (size_t)(p - (char*)d_ws);
    if (ws_size < need) return;

    ushort_t* Aim   = (ushort_t*)y32;  // im2col overlays y32 (dead until scan)
    ushort_t* ynorm = xbc;             // overlays xbc (dead after scan)
    float* tmp      = y32;             // unembed output overlays y32 (dead after fixnorm)

    k_castpad<<<256, 384, 0, stream>>>(patch_w, Wt_p);
    k_transcast<<<1152, 256, 0, stream>>>(W_in, Wt_in, 256, 1064);
    k_transcast<<<256, 256, 0, stream>>>(W_out, Wt_out, 512, 256);
    k_transcast<<<384, 256, 0, stream>>>(unemb_w, Wt_un, 256, 368);

    k_im2col<<<dim3(32, 8, 4), 256, 0, stream>>>(x, Aim);
    k_mgemm<384, 256, true><<<dim3(2, 256), 256, 0, stream>>>(Aim, 384, Wt_p, xs, 256, 0, patch_b);

    // in-proj split: z cols 0..511 -> z_bf bf16; xBC+dt cols 512..1063 -> xbcdt bf16
    k_mgemm<256, 512, true><<<dim3(4, 256), 256, 0, stream>>>(xs, 256, Wt_in, z_bf, 512, 0, nullptr);
    k_mgemm<256, 552, true><<<dim3(5, 256), 256, 0, stream>>>(xs, 256, Wt_in + (size_t)512 * 256, xbcdt, 640, 0, nullptr);

    k_conv<<<BLROWS / 8, 256, 0, stream>>>(xbcdt, conv_w, conv_b, dt_bias, A_log, xbc, bc32, dtv, dAv);

    k_scan_chunk<<<dim3(NCH, 2, 4), 256, 0, stream>>>(xbc, bc32, dtv, dAv, D_param, y32, cdv, sbuf);
    k_chain<<<dim3(8, 4), 256, 0, stream>>>(sbuf, cdv, hin);

    k_fixnorm<<<BLROWS, 256, 0, stream>>>(y32, z_bf, bc32, cdv, hin, norm_w, ynorm);

    k_mgemm<512, 256, true><<<dim3(2, 256), 256, 0, stream>>>(ynorm, 512, Wt_out, xs, DM_, 0, nullptr);

    k_mgemm<256, 368, false><<<dim3(3, 256), 256, 0, stream>>>(xs, 256, Wt_un, tmp, KPATCH, 0, nullptr);

    k_scatter<<<dim3(64, 184, 4), 256, 0, stream>>>(tmp, unemb_b, x, out);
}

// Round 7
// 323.148 us; speedup vs baseline: 6.7548x; 1.0947x over previous
//
#include <hip/hip_runtime.h>
#include <hip/hip_bf16.h>
#include <cstdint>
#include <cstddef>

// ---- problem constants ----
#define B_N       4
#define C_INCH    23
#define T_N       8
#define W_IMG     128
#define L_SEQ     8192
#define BLROWS    32768      // B_N * L_SEQ
#define DM_       256
#define D_INNER_  512
#define CONV_DIM_ 544
#define D_PROJ    1064
#define KPATCH    368        // C_INCH*4*4
#define QCH       128        // scan chunk length
#define NCH       64         // chunks per batch

typedef unsigned short ushort_t;
typedef unsigned int uint_t;
typedef __attribute__((ext_vector_type(8))) short short8;
typedef __attribute__((ext_vector_type(4))) float f32x4;

__device__ __forceinline__ float b2f(ushort_t u) {
    union { float f; uint_t u; } v; v.u = ((uint_t)u) << 16; return v.f;
}
__device__ __forceinline__ ushort_t f2b(float f) {
    union { float f; uint_t u; } v; v.f = f;
    uint_t r = v.u + 0x7fffu + ((v.u >> 16) & 1u);
    return (ushort_t)(r >> 16);
}

// async global->LDS, 16B per lane. LDS dest = wave-uniform base + lane*16.
__device__ __forceinline__ void gload_lds16(const ushort_t* g, ushort_t* l) {
    __builtin_amdgcn_global_load_lds(
        (const __attribute__((address_space(1))) unsigned int*)g,
        (__attribute__((address_space(3))) unsigned int*)l, 16, 0, 0);
}

// ---------------------------------------------------------------
// weight prep: dst[Npad][K] bf16 = transpose(src[K][N] fp32) * (rscale?rscale[k]:1)
__global__ void k_transcast(const float* __restrict__ src, ushort_t* __restrict__ dst,
                            int K, int N, const float* __restrict__ rscale) {
    int n = blockIdx.x;
    for (int k = threadIdx.x; k < K; k += 256) {
        float v = 0.f;
        if (n < N) {
            v = src[(size_t)k * N + n];
            if (rscale) v *= rscale[k];
        }
        dst[(size_t)n * K + k] = f2b(v);
    }
}

// patch weights are already [d][k]: direct cast + pad k to 384
__global__ void k_castpad(const float* __restrict__ src, ushort_t* __restrict__ dst) {
    int d = blockIdx.x; int k = threadIdx.x;   // 384 threads
    dst[d * 384 + k] = (k < KPATCH) ? f2b(src[d * KPATCH + k]) : (ushort_t)0;
}

// ---------------------------------------------------------------
// im2col gather: Aim[row][384] bf16, row=(b,t,hp,wp), kk=c*16+i*4+j; kk>=368 -> 0
__global__ void __launch_bounds__(256) k_im2col(const float* __restrict__ x,
                                                ushort_t* __restrict__ Aim) {
    int hp = blockIdx.x, t = blockIdx.y, b = blockIdx.z;
    int tid = threadIdx.x;
    int half = tid >> 7, q = tid & 127;
    int wp = q >> 2, j = q & 3;
    size_t rowbase = (size_t)b * L_SEQ + t * 1024 + hp * 32;
    #pragma unroll
    for (int it = 0; it < 2; ++it) {
        int idx = it * 256 + tid;
        int wpz = idx >> 4, kz = KPATCH + (idx & 15);
        Aim[(rowbase + wpz) * 384 + kz] = 0;
    }
    for (int s2 = 0; s2 < 46; ++s2) {
        int seg = s2 * 2 + half;            // c*4+i
        int c = seg >> 2, i = seg & 3;
        float v = x[(((size_t)(b * C_INCH + c) * T_N + t) << 14) + (size_t)(hp * 4 + i) * W_IMG + q];
        Aim[(rowbase + wp) * 384 + c * 16 + i * 4 + j] = f2b(v);
    }
}

// ---------------------------------------------------------------
// MFMA GEMM: C[M,N] = A[M,K](bf16) @ Wt[n][k](bf16, padded rows) [+bias[n]] [*rowscale[m]].
// 128x128 tile, 4 waves (2x2 of 64x64), BK=64, global_load_lds staging, XOR-swizzled LDS.
template <int K, int N, bool CBF>
__global__ void __launch_bounds__(256) k_mgemm(const ushort_t* __restrict__ A, const int lda,
                                               const ushort_t* __restrict__ Wt,
                                               void* __restrict__ Cv, const int ldc, const int coff,
                                               const float* __restrict__ bias,
                                               const float* __restrict__ rowscale) {
    __shared__ ushort_t Al[128 * 64];
    __shared__ ushort_t Bl[128 * 64];
    const int tid = threadIdx.x;
    const int w = tid >> 6, lane = tid & 63;
    const int wr = w >> 1, wc = w & 1;
    const int rowbase = blockIdx.y * 128;
    const int colbase = blockIdx.x * 128;
    const int g = lane >> 4, r = lane & 15;

    f32x4 acc[4][4];
    #pragma unroll
    for (int i = 0; i < 4; ++i)
        #pragma unroll
        for (int j = 0; j < 4; ++j) acc[i][j] = (f32x4){0.f, 0.f, 0.f, 0.f};

    for (int k0 = 0; k0 < K; k0 += 64) {
        __syncthreads();
        #pragma unroll
        for (int it = 0; it < 4; ++it) {
            int s = it * 256 + (w << 6) + lane;
            int row = s >> 3;
            int c16 = (s & 7) ^ (row & 7);
            gload_lds16(A + (size_t)(rowbase + row) * lda + k0 + c16 * 8,
                        &Al[(size_t)(it * 256 + (w << 6)) * 8]);
        }
        #pragma unroll
        for (int it = 0; it < 4; ++it) {
            int s = it * 256 + (w << 6) + lane;
            int row = s >> 3;
            int c16 = (s & 7) ^ (row & 7);
            gload_lds16(Wt + (size_t)(colbase + row) * K + k0 + c16 * 8,
                        &Bl[(size_t)(it * 256 + (w << 6)) * 8]);
        }
        __syncthreads();

        short8 af[2][4], bf[2][4];
        #pragma unroll
        for (int ks = 0; ks < 2; ++ks)
            #pragma unroll
            for (int mi = 0; mi < 4; ++mi) {
                int row = (wr << 6) + (mi << 4) + r;
                int c16 = ((ks << 2) | g) ^ (row & 7);
                af[ks][mi] = *(const short8*)&Al[(size_t)((row << 3) + c16) * 8];
            }
        #pragma unroll
        for (int ks = 0; ks < 2; ++ks)
            #pragma unroll
            for (int ni = 0; ni < 4; ++ni) {
                int row = (wc << 6) + (ni << 4) + r;
                int c16 = ((ks << 2) | g) ^ (row & 7);
                bf[ks][ni] = *(const short8*)&Bl[(size_t)((row << 3) + c16) * 8];
            }
        #pragma unroll
        for (int ks = 0; ks < 2; ++ks)
            #pragma unroll
            for (int mi = 0; mi < 4; ++mi)
                #pragma unroll
                for (int ni = 0; ni < 4; ++ni)
                    acc[mi][ni] = __builtin_amdgcn_mfma_f32_16x16x32_bf16(
                        af[ks][mi], bf[ks][ni], acc[mi][ni], 0, 0, 0);
    }

    // C store: D col=lane&15, row=(lane>>4)*4+reg
    #pragma unroll
    for (int mi = 0; mi < 4; ++mi) {
        int rw = rowbase + (wr << 6) + (mi << 4) + (g << 2);
        float s0 = 1.f, s1 = 1.f, s2 = 1.f, s3 = 1.f;
        if (rowscale) { s0 = rowscale[rw]; s1 = rowscale[rw+1]; s2 = rowscale[rw+2]; s3 = rowscale[rw+3]; }
        #pragma unroll
        for (int ni = 0; ni < 4; ++ni) {
            int col = colbase + (wc << 6) + (ni << 4) + r;
            if (col < N) {
                float bv = bias ? bias[col] : 0.f;
                f32x4 v = acc[mi][ni];
                float vr[4] = {v[0]*s0 + bv, v[1]*s1 + bv, v[2]*s2 + bv, v[3]*s3 + bv};
                #pragma unroll
                for (int j = 0; j < 4; ++j) {
                    size_t cidx = (size_t)(rw + j) * ldc + coff + col;
                    if (CBF) ((ushort_t*)Cv)[cidx] = f2b(vr[j]);
                    else     ((float*)Cv)[cidx]   = vr[j];
                }
            }
        }
    }
}

// ---------------------------------------------------------------
// causal depthwise conv (kernel 4) + silu, sliding-window over 8 rows/block.
__global__ void __launch_bounds__(256) k_conv(const ushort_t* __restrict__ xbcdt,
                                              const float* __restrict__ cw,
                                              const float* __restrict__ cb,
                                              const float* __restrict__ dtb,
                                              const float* __restrict__ alog,
                                              ushort_t* __restrict__ xbc,
                                              float* __restrict__ bc32,
                                              float* __restrict__ dtv,
                                              float* __restrict__ dAv) {
    int tid = threadIdx.x;
    int rb = blockIdx.x * 8;            // first row of this block
    int srb = rb & (L_SEQ - 1);         // seq pos within batch
    #pragma unroll
    for (int it = 0; it < 3; ++it) {
        int ch = it * 256 + tid;
        if (ch >= 552) break;
        if (ch < CONV_DIM_) {
            float w0 = cw[ch * 4 + 0], w1 = cw[ch * 4 + 1];
            float w2 = cw[ch * 4 + 2], w3 = cw[ch * 4 + 3];
            float bias = cb[ch];
            float win[11];
            #pragma unroll
            for (int j = 0; j < 11; ++j) {
                int sj = srb + j - 3;
                win[j] = (sj >= 0) ? b2f(xbcdt[(size_t)(rb + j - 3) * 640 + ch]) : 0.f;
            }
            #pragma unroll
            for (int r = 0; r < 8; ++r) {
                float acc = bias + win[r] * w0 + win[r + 1] * w1 + win[r + 2] * w2 + win[r + 3] * w3;
                float s = acc / (1.f + __expf(-acc));
                size_t row = rb + r;
                if (ch < 512) xbc[row * 512 + ch] = f2b(s);
                else          bc32[row * 32 + (ch - 512)] = s;
            }
        } else {
            int h = ch - CONV_DIM_;
            float A = -__expf(alog[h]);
            float db = dtb[h];
            #pragma unroll
            for (int r = 0; r < 8; ++r) {
                size_t row = rb + r;
                float v = b2f(xbcdt[row * 640 + ch]) + db;
                float sp = (v > 20.f) ? v : log1pf(__expf(v));
                dtv[row * 8 + h] = sp;
                dAv[row * 8 + h] = __expf(sp * A);
            }
        }
    }
}

// ---------------------------------------------------------------
// scan phase 1: chunk-final local states ONLY (from zero state) + per-chunk decay.
// block = 4 heads x 64 p; grid (NCH, 2, B).
__global__ void __launch_bounds__(256) k_scan1(const ushort_t* __restrict__ xbc,
                                               const float* __restrict__ bc32,
                                               const float* __restrict__ dtv,
                                               const float* __restrict__ dAv,
                                               float* __restrict__ sbuf,
                                               float* __restrict__ cdf) {
    int c = blockIdx.x, b = blockIdx.z;
    int tid = threadIdx.x;
    int h = blockIdx.y * 4 + (tid >> 6);
    int p = tid & 63;
    float st[16];
    #pragma unroll
    for (int n = 0; n < 16; ++n) st[n] = 0.f;
    float cd = 1.f;
    size_t row0 = (size_t)b * L_SEQ + (size_t)c * QCH;
    for (int s = 0; s < QCH; ++s) {
        size_t row = row0 + s;
        float da  = dAv[row * 8 + h];
        float dtt = dtv[row * 8 + h];
        float xh  = b2f(xbc[row * 512 + h * 64 + p]);
        const float4* B4 = (const float4*)(bc32 + row * 32);
        float xdt = xh * dtt;
        #pragma unroll
        for (int q = 0; q < 4; ++q) {
            float4 Bv = B4[q];
            st[q*4+0] = da * st[q*4+0] + xdt * Bv.x;
            st[q*4+1] = da * st[q*4+1] + xdt * Bv.y;
            st[q*4+2] = da * st[q*4+2] + xdt * Bv.z;
            st[q*4+3] = da * st[q*4+3] + xdt * Bv.w;
        }
        cd *= da;
    }
    size_t base = (((size_t)(b * 8 + h) * NCH + c) << 10) + p * 16;
    #pragma unroll
    for (int q = 0; q < 4; ++q)
        *(float4*)&sbuf[base + q * 4] = make_float4(st[q*4], st[q*4+1], st[q*4+2], st[q*4+3]);
    if (p == 0) cdf[(size_t)(b * 8 + h) * NCH + c] = cd;
}

// ---------------------------------------------------------------
// phase 2: sequential chain over chunks (tiny). block = (h, b); thread holds 4 states.
__global__ void __launch_bounds__(256) k_chain(const float* __restrict__ sbuf,
                                               const float* __restrict__ cdf,
                                               float* __restrict__ hin) {
    int h = blockIdx.x, b = blockIdx.y;
    int tid = threadIdx.x;
    float4 H = make_float4(0.f, 0.f, 0.f, 0.f);
    size_t base = ((size_t)(b * 8 + h) * NCH) << 10;
    for (int c = 0; c < NCH; ++c) {
        *(float4*)&hin[base + ((size_t)c << 10) + tid * 4] = H;
        float cdfv = cdf[(size_t)(b * 8 + h) * NCH + c];
        float4 S = *(const float4*)&sbuf[base + ((size_t)c << 10) + tid * 4];
        H.x = cdfv * H.x + S.x;
        H.y = cdfv * H.y + S.y;
        H.z = cdfv * H.z + S.z;
        H.w = cdfv * H.w + S.w;
    }
}

// ---------------------------------------------------------------
// scan phase 3: full re-scan from Hin (exact y, no fixup) + gate, in-place yg over xbc,
// per-wave sum(yg^2) partials -> psum[row][8].  block = 8 heads x 64 p; grid (NCH, B).
__global__ void __launch_bounds__(512) k_scan2(ushort_t* __restrict__ xbc,      // in: xh, out: yg (bf16)
                                               const ushort_t* __restrict__ z_bf,
                                               const float* __restrict__ bc32,
                                               const float* __restrict__ dtv,
                                               const float* __restrict__ dAv,
                                               const float* __restrict__ Dp,
                                               const float* __restrict__ hin,
                                               float* __restrict__ psum) {
    int c = blockIdx.x, b = blockIdx.y;
    int tid = threadIdx.x;
    int h = tid >> 6, p = tid & 63;
    float st[16];
    const float4* H = (const float4*)&hin[(((size_t)(b * 8 + h) * NCH + c) << 10) + p * 16];
    #pragma unroll
    for (int q = 0; q < 4; ++q) {
        float4 Hv = H[q];
        st[q*4+0] = Hv.x; st[q*4+1] = Hv.y; st[q*4+2] = Hv.z; st[q*4+3] = Hv.w;
    }
    float Dh = Dp[h];
    size_t row0 = (size_t)b * L_SEQ + (size_t)c * QCH;
    for (int s = 0; s < QCH; ++s) {
        size_t row = row0 + s;
        float da  = dAv[row * 8 + h];
        float dtt = dtv[row * 8 + h];
        float xh  = b2f(xbc[row * 512 + h * 64 + p]);
        const float4* B4 = (const float4*)(bc32 + row * 32);
        const float4* C4 = (const float4*)(bc32 + row * 32 + 16);
        float xdt = xh * dtt;
        float d0 = 0.f, d1 = 0.f, d2 = 0.f, d3 = 0.f;
        #pragma unroll
        for (int q = 0; q < 4; ++q) {
            float4 Bv = B4[q];
            float4 Cv = C4[q];
            st[q*4+0] = da * st[q*4+0] + xdt * Bv.x;
            st[q*4+1] = da * st[q*4+1] + xdt * Bv.y;
            st[q*4+2] = da * st[q*4+2] + xdt * Bv.z;
            st[q*4+3] = da * st[q*4+3] + xdt * Bv.w;
            d0 += st[q*4+0] * Cv.x;
            d1 += st[q*4+1] * Cv.y;
            d2 += st[q*4+2] * Cv.z;
            d3 += st[q*4+3] * Cv.w;
        }
        float y = (d0 + d1) + (d2 + d3) + Dh * xh;
        float z = b2f(z_bf[row * 512 + h * 64 + p]);
        float yg = y * (z / (1.f + __expf(-z)));
        float sq = yg * yg;
        #pragma unroll
        for (int off = 32; off >= 1; off >>= 1) sq += __shfl_xor(sq, off);
        if (p == 0) psum[row * 8 + h] = sq;
        xbc[row * 512 + h * 64 + p] = f2b(yg);
    }
}

// ---------------------------------------------------------------
// row scale: scale[row] = rsqrt(mean(yg^2) + eps)
__global__ void __launch_bounds__(256) k_rsum(const float* __restrict__ psum,
                                              float* __restrict__ scale) {
    int row = blockIdx.x * 256 + threadIdx.x;
    const float4* p4 = (const float4*)(psum + (size_t)row * 8);
    float4 a = p4[0], bq = p4[1];
    float tot = (a.x + a.y + a.z + a.w) + (bq.x + bq.y + bq.z + bq.w);
    scale[row] = rsqrtf(tot * (1.f / 512.f) + 1e-5f);
}

// ---------------------------------------------------------------
__global__ void __launch_bounds__(256) k_scatter(const float* __restrict__ tmp,
                                                 const float* __restrict__ ub,
                                                 const float* __restrict__ xin,
                                                 float* __restrict__ out) {
    int tid = threadIdx.x;
    int w = tid & 127;
    int h = (blockIdx.x << 1) | (tid >> 7);
    int c = blockIdx.y >> 3, t = blockIdx.y & 7;
    int b = blockIdx.z;
    size_t row = (size_t)b * L_SEQ + t * 1024 + (h >> 2) * 32 + (w >> 2);
    int kk = c * 16 + (h & 3) * 4 + (w & 3);
    size_t oidx = (((size_t)(b * C_INCH + c) * T_N + t) << 14) + (size_t)h * W_IMG + w;
    out[oidx] = tmp[row * KPATCH + kk] + ub[c] + xin[oidx];
}

// ---------------------------------------------------------------
extern "C" void kernel_launch(void* const* d_in, const int* in_sizes, int n_in,
                              void* d_out, int out_size, void* d_ws, size_t ws_size,
                              hipStream_t stream) {
    const float* x       = (const float*)d_in[0];
    const float* patch_w = (const float*)d_in[1];
    const float* patch_b = (const float*)d_in[2];
    const float* W_in    = (const float*)d_in[3];
    const float* conv_w  = (const float*)d_in[4];
    const float* conv_b  = (const float*)d_in[5];
    const float* dt_bias = (const float*)d_in[6];
    const float* A_log   = (const float*)d_in[7];
    const float* D_param = (const float*)d_in[8];
    const float* norm_w  = (const float*)d_in[9];
    const float* W_out   = (const float*)d_in[10];
    const float* unemb_w = (const float*)d_in[11];
    const float* unemb_b = (const float*)d_in[12];
    float* out = (float*)d_out;

    // ---- workspace carve ----
    char* p = (char*)d_ws;
    float* scratch = (float*)p; p += (size_t)BLROWS * 512 * 4;       // 67 MB (Aim / tmp overlay)
    float* dtv  = (float*)p;   p += (size_t)BLROWS * 8 * 4;
    float* dAv  = (float*)p;   p += (size_t)BLROWS * 8 * 4;
    float* psum = (float*)p;   p += (size_t)BLROWS * 8 * 4;          // 1 MB
    float* scale= (float*)p;   p += (size_t)BLROWS * 4;              // 128 KB
    float* cdf  = (float*)p;   p += (size_t)32 * NCH * 4;            // 8 KB
    float* sbuf = (float*)p;   p += (size_t)32 * NCH * 1024 * 4;     // 8.4 MB
    float* hin  = (float*)p;   p += (size_t)32 * NCH * 1024 * 4;     // 8.4 MB
    float* bc32 = (float*)p;   p += (size_t)BLROWS * 32 * 4;         // 4.2 MB
    ushort_t* Wt_p   = (ushort_t*)p; p += (size_t)256 * 384 * 2;
    ushort_t* Wt_in  = (ushort_t*)p; p += (size_t)1152 * 256 * 2;
    ushort_t* Wt_out = (ushort_t*)p; p += (size_t)256 * 512 * 2;
    ushort_t* Wt_un  = (ushort_t*)p; p += (size_t)384 * 256 * 2;
    ushort_t* xs     = (ushort_t*)p; p += (size_t)BLROWS * DM_ * 2;  // 16.8 MB
    ushort_t* xbc    = (ushort_t*)p; p += (size_t)BLROWS * 512 * 2;  // 33.5 MB (xh -> yg in place)
    ushort_t* z_bf   = (ushort_t*)p; p += (size_t)BLROWS * 512 * 2;  // 33.5 MB
    ushort_t* xbcdt  = (ushort_t*)p; p += (size_t)BLROWS * 640 * 2;  // 41.9 MB
    size_t need = (size_t)(p - (char*)d_ws);
    if (ws_size < need) return;

    ushort_t* Aim = (ushort_t*)scratch;  // im2col (dead after patch GEMM)
    float* tmp    = scratch;             // unembed output (dead until unembed)

    k_castpad<<<256, 384, 0, stream>>>(patch_w, Wt_p);
    k_transcast<<<1152, 256, 0, stream>>>(W_in, Wt_in, 256, 1064, nullptr);
    k_transcast<<<256, 256, 0, stream>>>(W_out, Wt_out, 512, 256, norm_w);  // fold RMSNorm weight
    k_transcast<<<384, 256, 0, stream>>>(unemb_w, Wt_un, 256, 368, nullptr);

    k_im2col<<<dim3(32, 8, 4), 256, 0, stream>>>(x, Aim);
    k_mgemm<384, 256, true><<<dim3(2, 256), 256, 0, stream>>>(Aim, 384, Wt_p, xs, 256, 0, patch_b, nullptr);

    // in-proj split: z cols 0..511 -> z_bf; xBC+dt cols 512..1063 -> xbcdt
    k_mgemm<256, 512, true><<<dim3(4, 256), 256, 0, stream>>>(xs, 256, Wt_in, z_bf, 512, 0, nullptr, nullptr);
    k_mgemm<256, 552, true><<<dim3(5, 256), 256, 0, stream>>>(xs, 256, Wt_in + (size_t)512 * 256, xbcdt, 640, 0, nullptr, nullptr);

    k_conv<<<BLROWS / 8, 256, 0, stream>>>(xbcdt, conv_w, conv_b, dt_bias, A_log, xbc, bc32, dtv, dAv);

    k_scan1<<<dim3(NCH, 2, 4), 256, 0, stream>>>(xbc, bc32, dtv, dAv, sbuf, cdf);
    k_chain<<<dim3(8, 4), 256, 0, stream>>>(sbuf, cdf, hin);
    k_scan2<<<dim3(NCH, 4), 512, 0, stream>>>(xbc, z_bf, bc32, dtv, dAv, D_param, hin, psum);
    k_rsum<<<BLROWS / 256, 256, 0, stream>>>(psum, scale);

    // out-proj with fused RMSNorm row-scale: out_seq bf16 -> xs
    k_mgemm<512, 256, true><<<dim3(2, 256), 256, 0, stream>>>(xbc, 512, Wt_out, xs, DM_, 0, nullptr, scale);

    k_mgemm<256, 368, false><<<dim3(3, 256), 256, 0, stream>>>(xs, 256, Wt_un, tmp, KPATCH, 0, nullptr, nullptr);

    k_scatter<<<dim3(64, 184, 4), 256, 0, stream>>>(tmp, unemb_b, x, out);
}

// Round 8
// 287.025 us; speedup vs baseline: 7.6049x; 1.1259x over previous
//
#include <hip/hip_runtime.h>
#include <hip/hip_bf16.h>
#include <cstdint>
#include <cstddef>

// ---- problem constants ----
#define B_N       4
#define C_INCH    23
#define T_N       8
#define W_IMG     128
#define L_SEQ     8192
#define BLROWS    32768      // B_N * L_SEQ
#define DM_       256
#define D_INNER_  512
#define CONV_DIM_ 544
#define D_PROJ    1064
#define KPATCH    368        // C_INCH*4*4
#define QCH       64         // scan chunk length
#define NCH       128        // chunks per batch

typedef unsigned short ushort_t;
typedef unsigned int uint_t;
typedef __attribute__((ext_vector_type(8))) short short8;
typedef __attribute__((ext_vector_type(4))) float f32x4;

__device__ __forceinline__ float b2f(ushort_t u) {
    union { float f; uint_t u; } v; v.u = ((uint_t)u) << 16; return v.f;
}
__device__ __forceinline__ ushort_t f2b(float f) {
    union { float f; uint_t u; } v; v.f = f;
    uint_t r = v.u + 0x7fffu + ((v.u >> 16) & 1u);
    return (ushort_t)(r >> 16);
}

// async global->LDS, 16B per lane. LDS dest = wave-uniform base + lane*16.
__device__ __forceinline__ void gload_lds16(const ushort_t* g, ushort_t* l) {
    __builtin_amdgcn_global_load_lds(
        (const __attribute__((address_space(1))) unsigned int*)g,
        (__attribute__((address_space(3))) unsigned int*)l, 16, 0, 0);
}

// ---------------------------------------------------------------
// weight prep: dst[Npad][K] bf16 = transpose(src[K][N] fp32) * (rscale?rscale[k]:1)
__global__ void k_transcast(const float* __restrict__ src, ushort_t* __restrict__ dst,
                            int K, int N, const float* __restrict__ rscale) {
    int n = blockIdx.x;
    for (int k = threadIdx.x; k < K; k += 256) {
        float v = 0.f;
        if (n < N) {
            v = src[(size_t)k * N + n];
            if (rscale) v *= rscale[k];
        }
        dst[(size_t)n * K + k] = f2b(v);
    }
}

// patch weights are already [d][k]: direct cast + pad k to 384
__global__ void k_castpad(const float* __restrict__ src, ushort_t* __restrict__ dst) {
    int d = blockIdx.x; int k = threadIdx.x;   // 384 threads
    dst[d * 384 + k] = (k < KPATCH) ? f2b(src[d * KPATCH + k]) : (ushort_t)0;
}

// ---------------------------------------------------------------
// im2col gather: Aim[row][384] bf16, row=(b,t,hp,wp), kk=c*16+i*4+j; kk>=368 -> 0
__global__ void __launch_bounds__(256) k_im2col(const float* __restrict__ x,
                                                ushort_t* __restrict__ Aim) {
    int hp = blockIdx.x, t = blockIdx.y, b = blockIdx.z;
    int tid = threadIdx.x;
    int half = tid >> 7, q = tid & 127;
    int wp = q >> 2, j = q & 3;
    size_t rowbase = (size_t)b * L_SEQ + t * 1024 + hp * 32;
    #pragma unroll
    for (int it = 0; it < 2; ++it) {
        int idx = it * 256 + tid;
        int wpz = idx >> 4, kz = KPATCH + (idx & 15);
        Aim[(rowbase + wpz) * 384 + kz] = 0;
    }
    for (int s2 = 0; s2 < 46; ++s2) {
        int seg = s2 * 2 + half;            // c*4+i
        int c = seg >> 2, i = seg & 3;
        float v = x[(((size_t)(b * C_INCH + c) * T_N + t) << 14) + (size_t)(hp * 4 + i) * W_IMG + q];
        Aim[(rowbase + wp) * 384 + c * 16 + i * 4 + j] = f2b(v);
    }
}

// ---------------------------------------------------------------
// MFMA GEMM: C[M,N] = A[M,K](bf16) @ Wt[n][k](bf16, padded rows) [+bias[n]] [*rowscale[m]].
// 128x128 tile, 4 waves (2x2 of 64x64), BK=64, global_load_lds staging, XOR-swizzled LDS.
template <int K, int N, bool CBF>
__global__ void __launch_bounds__(256) k_mgemm(const ushort_t* __restrict__ A, const int lda,
                                               const ushort_t* __restrict__ Wt,
                                               void* __restrict__ Cv, const int ldc, const int coff,
                                               const float* __restrict__ bias,
                                               const float* __restrict__ rowscale) {
    __shared__ ushort_t Al[128 * 64];
    __shared__ ushort_t Bl[128 * 64];
    const int tid = threadIdx.x;
    const int w = tid >> 6, lane = tid & 63;
    const int wr = w >> 1, wc = w & 1;
    const int rowbase = blockIdx.y * 128;
    const int colbase = blockIdx.x * 128;
    const int g = lane >> 4, r = lane & 15;

    f32x4 acc[4][4];
    #pragma unroll
    for (int i = 0; i < 4; ++i)
        #pragma unroll
        for (int j = 0; j < 4; ++j) acc[i][j] = (f32x4){0.f, 0.f, 0.f, 0.f};

    for (int k0 = 0; k0 < K; k0 += 64) {
        __syncthreads();
        #pragma unroll
        for (int it = 0; it < 4; ++it) {
            int s = it * 256 + (w << 6) + lane;
            int row = s >> 3;
            int c16 = (s & 7) ^ (row & 7);
            gload_lds16(A + (size_t)(rowbase + row) * lda + k0 + c16 * 8,
                        &Al[(size_t)(it * 256 + (w << 6)) * 8]);
        }
        #pragma unroll
        for (int it = 0; it < 4; ++it) {
            int s = it * 256 + (w << 6) + lane;
            int row = s >> 3;
            int c16 = (s & 7) ^ (row & 7);
            gload_lds16(Wt + (size_t)(colbase + row) * K + k0 + c16 * 8,
                        &Bl[(size_t)(it * 256 + (w << 6)) * 8]);
        }
        __syncthreads();

        short8 af[2][4], bf[2][4];
        #pragma unroll
        for (int ks = 0; ks < 2; ++ks)
            #pragma unroll
            for (int mi = 0; mi < 4; ++mi) {
                int row = (wr << 6) + (mi << 4) + r;
                int c16 = ((ks << 2) | g) ^ (row & 7);
                af[ks][mi] = *(const short8*)&Al[(size_t)((row << 3) + c16) * 8];
            }
        #pragma unroll
        for (int ks = 0; ks < 2; ++ks)
            #pragma unroll
            for (int ni = 0; ni < 4; ++ni) {
                int row = (wc << 6) + (ni << 4) + r;
                int c16 = ((ks << 2) | g) ^ (row & 7);
                bf[ks][ni] = *(const short8*)&Bl[(size_t)((row << 3) + c16) * 8];
            }
        #pragma unroll
        for (int ks = 0; ks < 2; ++ks)
            #pragma unroll
            for (int mi = 0; mi < 4; ++mi)
                #pragma unroll
                for (int ni = 0; ni < 4; ++ni)
                    acc[mi][ni] = __builtin_amdgcn_mfma_f32_16x16x32_bf16(
                        af[ks][mi], bf[ks][ni], acc[mi][ni], 0, 0, 0);
    }

    // C store: D col=lane&15, row=(lane>>4)*4+reg
    #pragma unroll
    for (int mi = 0; mi < 4; ++mi) {
        int rw = rowbase + (wr << 6) + (mi << 4) + (g << 2);
        float s0 = 1.f, s1 = 1.f, s2 = 1.f, s3 = 1.f;
        if (rowscale) { s0 = rowscale[rw]; s1 = rowscale[rw+1]; s2 = rowscale[rw+2]; s3 = rowscale[rw+3]; }
        #pragma unroll
        for (int ni = 0; ni < 4; ++ni) {
            int col = colbase + (wc << 6) + (ni << 4) + r;
            if (col < N) {
                float bv = bias ? bias[col] : 0.f;
                f32x4 v = acc[mi][ni];
                float vr[4] = {v[0]*s0 + bv, v[1]*s1 + bv, v[2]*s2 + bv, v[3]*s3 + bv};
                #pragma unroll
                for (int j = 0; j < 4; ++j) {
                    size_t cidx = (size_t)(rw + j) * ldc + coff + col;
                    if (CBF) ((ushort_t*)Cv)[cidx] = f2b(vr[j]);
                    else     ((float*)Cv)[cidx]   = vr[j];
                }
            }
        }
    }
}

// ---------------------------------------------------------------
// causal depthwise conv (kernel 4) + silu, sliding-window over 8 rows/block.
__global__ void __launch_bounds__(256) k_conv(const ushort_t* __restrict__ xbcdt,
                                              const float* __restrict__ cw,
                                              const float* __restrict__ cb,
                                              const float* __restrict__ dtb,
                                              const float* __restrict__ alog,
                                              ushort_t* __restrict__ xbc,
                                              float* __restrict__ bc32,
                                              float* __restrict__ dtv,
                                              float* __restrict__ dAv) {
    int tid = threadIdx.x;
    int rb = blockIdx.x * 8;            // first row of this block
    int srb = rb & (L_SEQ - 1);         // seq pos within batch
    #pragma unroll
    for (int it = 0; it < 3; ++it) {
        int ch = it * 256 + tid;
        if (ch >= 552) break;
        if (ch < CONV_DIM_) {
            float w0 = cw[ch * 4 + 0], w1 = cw[ch * 4 + 1];
            float w2 = cw[ch * 4 + 2], w3 = cw[ch * 4 + 3];
            float bias = cb[ch];
            float win[11];
            #pragma unroll
            for (int j = 0; j < 11; ++j) {
                int sj = srb + j - 3;
                win[j] = (sj >= 0) ? b2f(xbcdt[(size_t)(rb + j - 3) * 640 + ch]) : 0.f;
            }
            #pragma unroll
            for (int r = 0; r < 8; ++r) {
                float acc = bias + win[r] * w0 + win[r + 1] * w1 + win[r + 2] * w2 + win[r + 3] * w3;
                float s = acc / (1.f + __expf(-acc));
                size_t row = rb + r;
                if (ch < 512) xbc[row * 512 + ch] = f2b(s);
                else          bc32[row * 32 + (ch - 512)] = s;
            }
        } else {
            int h = ch - CONV_DIM_;
            float A = -__expf(alog[h]);
            float db = dtb[h];
            #pragma unroll
            for (int r = 0; r < 8; ++r) {
                size_t row = rb + r;
                float v = b2f(xbcdt[row * 640 + ch]) + db;
                float sp = (v > 20.f) ? v : log1pf(__expf(v));
                dtv[row * 8 + h] = sp;
                dAv[row * 8 + h] = __expf(sp * A);
            }
        }
    }
}

// ---------------------------------------------------------------
// scan phase 1: chunk-final local states ONLY (from zero state) + per-chunk decay.
// block = 4 heads x 64 p; grid (NCH, 2, B).
__global__ void __launch_bounds__(256) k_scan1(const ushort_t* __restrict__ xbc,
                                               const float* __restrict__ bc32,
                                               const float* __restrict__ dtv,
                                               const float* __restrict__ dAv,
                                               float* __restrict__ sbuf,
                                               float* __restrict__ cdf) {
    int c = blockIdx.x, b = blockIdx.z;
    int tid = threadIdx.x;
    int h = blockIdx.y * 4 + (tid >> 6);
    int p = tid & 63;
    float st[16];
    #pragma unroll
    for (int n = 0; n < 16; ++n) st[n] = 0.f;
    float cd = 1.f;
    size_t row0 = (size_t)b * L_SEQ + (size_t)c * QCH;
    for (int s = 0; s < QCH; ++s) {
        size_t row = row0 + s;
        float da  = dAv[row * 8 + h];
        float dtt = dtv[row * 8 + h];
        float xh  = b2f(xbc[row * 512 + h * 64 + p]);
        const float4* B4 = (const float4*)(bc32 + row * 32);
        float xdt = xh * dtt;
        #pragma unroll
        for (int q = 0; q < 4; ++q) {
            float4 Bv = B4[q];
            st[q*4+0] = da * st[q*4+0] + xdt * Bv.x;
            st[q*4+1] = da * st[q*4+1] + xdt * Bv.y;
            st[q*4+2] = da * st[q*4+2] + xdt * Bv.z;
            st[q*4+3] = da * st[q*4+3] + xdt * Bv.w;
        }
        cd *= da;
    }
    size_t base = (size_t)((b * 8 + h) * NCH + c) * 1024 + p * 16;
    #pragma unroll
    for (int q = 0; q < 4; ++q)
        *(float4*)&sbuf[base + q * 4] = make_float4(st[q*4], st[q*4+1], st[q*4+2], st[q*4+3]);
    if (p == 0) cdf[(b * 8 + h) * NCH + c] = cd;
}

// ---------------------------------------------------------------
// phase 2: sequential chain over chunks (tiny). block = (h, b); thread holds 4 states.
__global__ void __launch_bounds__(256) k_chain(const float* __restrict__ sbuf,
                                               const float* __restrict__ cdf,
                                               float* __restrict__ hin) {
    int h = blockIdx.x, b = blockIdx.y;
    int tid = threadIdx.x;
    float4 H = make_float4(0.f, 0.f, 0.f, 0.f);
    size_t base = (size_t)((b * 8 + h) * NCH) * 1024;
    for (int c = 0; c < NCH; ++c) {
        *(float4*)&hin[base + (size_t)c * 1024 + tid * 4] = H;
        float cdfv = cdf[(b * 8 + h) * NCH + c];
        float4 S = *(const float4*)&sbuf[base + (size_t)c * 1024 + tid * 4];
        H.x = cdfv * H.x + S.x;
        H.y = cdfv * H.y + S.y;
        H.z = cdfv * H.z + S.z;
        H.w = cdfv * H.w + S.w;
    }
}

// ---------------------------------------------------------------
// scan phase 3: full re-scan from Hin (exact y) + gate; yg -> SEPARATE buffer
// (no aliasing with inputs -> cross-step prefetch possible). Manual 1-step
// software pipeline; the one-row overread on the final step lands in adjacent
// workspace buffers (safe, values unused). block = 8 heads x 64 p; grid (NCH, B).
__global__ void __launch_bounds__(512) k_scan2(const ushort_t* __restrict__ xbc,
                                               const ushort_t* __restrict__ z_bf,
                                               const float* __restrict__ bc32,
                                               const float* __restrict__ dtv,
                                               const float* __restrict__ dAv,
                                               const float* __restrict__ Dp,
                                               const float* __restrict__ hin,
                                               ushort_t* __restrict__ yg_out) {
    int c = blockIdx.x, b = blockIdx.y;
    int tid = threadIdx.x;
    int h = tid >> 6, p = tid & 63;
    int off = h * 64 + p;
    float st[16];
    const float4* H = (const float4*)&hin[(size_t)((b * 8 + h) * NCH + c) * 1024 + p * 16];
    #pragma unroll
    for (int q = 0; q < 4; ++q) {
        float4 Hv = H[q];
        st[q*4+0] = Hv.x; st[q*4+1] = Hv.y; st[q*4+2] = Hv.z; st[q*4+3] = Hv.w;
    }
    float Dh = Dp[h];
    size_t row = (size_t)b * L_SEQ + (size_t)c * QCH;

    // prologue loads (step 0)
    float da  = dAv[row * 8 + h];
    float dtt = dtv[row * 8 + h];
    float xh  = b2f(xbc[row * 512 + off]);
    float zz  = b2f(z_bf[row * 512 + off]);
    float4 Bc[4], Cc[4];
    {
        const float4* B4 = (const float4*)(bc32 + row * 32);
        #pragma unroll
        for (int q = 0; q < 4; ++q) { Bc[q] = B4[q]; Cc[q] = B4[q + 4]; }
    }

    for (int s = 0; s < QCH; ++s) {
        // issue next-step loads (overread on last iter is safe: stays in d_ws)
        size_t rn = row + 1;
        float da_n  = dAv[rn * 8 + h];
        float dt_n  = dtv[rn * 8 + h];
        float xh_n  = b2f(xbc[rn * 512 + off]);
        float zz_n  = b2f(z_bf[rn * 512 + off]);
        float4 Bn[4], Cn[4];
        const float4* B4n = (const float4*)(bc32 + rn * 32);
        #pragma unroll
        for (int q = 0; q < 4; ++q) { Bn[q] = B4n[q]; Cn[q] = B4n[q + 4]; }

        // compute current step
        float xdt = xh * dtt;
        float d0 = 0.f, d1 = 0.f, d2 = 0.f, d3 = 0.f;
        #pragma unroll
        for (int q = 0; q < 4; ++q) {
            st[q*4+0] = da * st[q*4+0] + xdt * Bc[q].x;
            st[q*4+1] = da * st[q*4+1] + xdt * Bc[q].y;
            st[q*4+2] = da * st[q*4+2] + xdt * Bc[q].z;
            st[q*4+3] = da * st[q*4+3] + xdt * Bc[q].w;
            d0 += st[q*4+0] * Cc[q].x;
            d1 += st[q*4+1] * Cc[q].y;
            d2 += st[q*4+2] * Cc[q].z;
            d3 += st[q*4+3] * Cc[q].w;
        }
        float y = (d0 + d1) + (d2 + d3) + Dh * xh;
        float yg = y * (zz / (1.f + __expf(-zz)));
        yg_out[row * 512 + off] = f2b(yg);

        // rotate pipeline
        row = rn; da = da_n; dtt = dt_n; xh = xh_n; zz = zz_n;
        #pragma unroll
        for (int q = 0; q < 4; ++q) { Bc[q] = Bn[q]; Cc[q] = Cn[q]; }
    }
}

// ---------------------------------------------------------------
// row scale from yg: scale[row] = rsqrt(mean(yg^2) + eps). one wave per row.
__global__ void __launch_bounds__(256) k_rsum(const ushort_t* __restrict__ yg,
                                              float* __restrict__ scale) {
    int wid = threadIdx.x >> 6, lane = threadIdx.x & 63;
    int row = blockIdx.x * 4 + wid;
    short8 v = *(const short8*)&yg[(size_t)row * 512 + lane * 8];
    float s = 0.f;
    #pragma unroll
    for (int j = 0; j < 8; ++j) {
        float f = b2f((ushort_t)v[j]);
        s += f * f;
    }
    #pragma unroll
    for (int off = 32; off >= 1; off >>= 1) s += __shfl_xor(s, off);
    if (lane == 0) scale[row] = rsqrtf(s * (1.f / 512.f) + 1e-5f);
}

// ---------------------------------------------------------------
__global__ void __launch_bounds__(256) k_scatter(const ushort_t* __restrict__ tmp,
                                                 const float* __restrict__ ub,
                                                 const float* __restrict__ xin,
                                                 float* __restrict__ out) {
    int tid = threadIdx.x;
    int w = tid & 127;
    int h = (blockIdx.x << 1) | (tid >> 7);
    int c = blockIdx.y >> 3, t = blockIdx.y & 7;
    int b = blockIdx.z;
    size_t row = (size_t)b * L_SEQ + t * 1024 + (h >> 2) * 32 + (w >> 2);
    int kk = c * 16 + (h & 3) * 4 + (w & 3);
    size_t oidx = (((size_t)(b * C_INCH + c) * T_N + t) << 14) + (size_t)h * W_IMG + w;
    out[oidx] = b2f(tmp[row * KPATCH + kk]) + ub[c] + xin[oidx];
}

// ---------------------------------------------------------------
extern "C" void kernel_launch(void* const* d_in, const int* in_sizes, int n_in,
                              void* d_out, int out_size, void* d_ws, size_t ws_size,
                              hipStream_t stream) {
    const float* x       = (const float*)d_in[0];
    const float* patch_w = (const float*)d_in[1];
    const float* patch_b = (const float*)d_in[2];
    const float* W_in    = (const float*)d_in[3];
    const float* conv_w  = (const float*)d_in[4];
    const float* conv_b  = (const float*)d_in[5];
    const float* dt_bias = (const float*)d_in[6];
    const float* A_log   = (const float*)d_in[7];
    const float* D_param = (const float*)d_in[8];
    const float* norm_w  = (const float*)d_in[9];
    const float* W_out   = (const float*)d_in[10];
    const float* unemb_w = (const float*)d_in[11];
    const float* unemb_b = (const float*)d_in[12];
    float* out = (float*)d_out;

    // ---- workspace carve ----
    char* p = (char*)d_ws;
    ushort_t* scratch = (ushort_t*)p; p += (size_t)BLROWS * 384 * 2;   // 25 MB (Aim / bf16 tmp)
    float* dtv  = (float*)p;   p += (size_t)BLROWS * 8 * 4;
    float* dAv  = (float*)p;   p += (size_t)BLROWS * 8 * 4;
    float* scale= (float*)p;   p += (size_t)BLROWS * 4;
    float* cdf  = (float*)p;   p += (size_t)32 * NCH * 4;
    float* sbuf = (float*)p;   p += (size_t)32 * NCH * 1024 * 4;       // 16.8 MB
    float* hin  = (float*)p;   p += (size_t)32 * NCH * 1024 * 4;       // 16.8 MB
    float* bc32 = (float*)p;   p += (size_t)BLROWS * 32 * 4;           // 4.2 MB
    ushort_t* Wt_p   = (ushort_t*)p; p += (size_t)256 * 384 * 2;
    ushort_t* Wt_in  = (ushort_t*)p; p += (size_t)1152 * 256 * 2;
    ushort_t* Wt_out = (ushort_t*)p; p += (size_t)256 * 512 * 2;
    ushort_t* Wt_un  = (ushort_t*)p; p += (size_t)384 * 256 * 2;
    ushort_t* xs     = (ushort_t*)p; p += (size_t)BLROWS * DM_ * 2;    // 16.8 MB
    ushort_t* xbc    = (ushort_t*)p; p += (size_t)BLROWS * 512 * 2;    // 33.5 MB
    ushort_t* z_bf   = (ushort_t*)p; p += (size_t)BLROWS * 512 * 2;    // 33.5 MB
    ushort_t* xbcdt  = (ushort_t*)p; p += (size_t)BLROWS * 640 * 2;    // 41.9 MB (later: yg)
    size_t need = (size_t)(p - (char*)d_ws);
    if (ws_size < need) return;

    ushort_t* Aim = scratch;            // im2col (dead after patch GEMM)
    ushort_t* tmp = scratch;            // bf16 unembed output (dead until unembed)
    ushort_t* yg  = xbcdt;              // yg overlays xbcdt (dead after conv)

    k_castpad<<<256, 384, 0, stream>>>(patch_w, Wt_p);
    k_transcast<<<1152, 256, 0, stream>>>(W_in, Wt_in, 256, 1064, nullptr);
    k_transcast<<<256, 256, 0, stream>>>(W_out, Wt_out, 512, 256, norm_w);  // fold RMSNorm weight
    k_transcast<<<384, 256, 0, stream>>>(unemb_w, Wt_un, 256, 368, nullptr);

    k_im2col<<<dim3(32, 8, 4), 256, 0, stream>>>(x, Aim);
    k_mgemm<384, 256, true><<<dim3(2, 256), 256, 0, stream>>>(Aim, 384, Wt_p, xs, 256, 0, patch_b, nullptr);

    // in-proj split: z cols 0..511 -> z_bf; xBC+dt cols 512..1063 -> xbcdt
    k_mgemm<256, 512, true><<<dim3(4, 256), 256, 0, stream>>>(xs, 256, Wt_in, z_bf, 512, 0, nullptr, nullptr);
    k_mgemm<256, 552, true><<<dim3(5, 256), 256, 0, stream>>>(xs, 256, Wt_in + (size_t)512 * 256, xbcdt, 640, 0, nullptr, nullptr);

    k_conv<<<BLROWS / 8, 256, 0, stream>>>(xbcdt, conv_w, conv_b, dt_bias, A_log, xbc, bc32, dtv, dAv);

    k_scan1<<<dim3(NCH, 2, 4), 256, 0, stream>>>(xbc, bc32, dtv, dAv, sbuf, cdf);
    k_chain<<<dim3(8, 4), 256, 0, stream>>>(sbuf, cdf, hin);
    k_scan2<<<dim3(NCH, 4), 512, 0, stream>>>(xbc, z_bf, bc32, dtv, dAv, D_param, hin, yg);
    k_rsum<<<BLROWS / 4, 256, 0, stream>>>(yg, scale);

    // out-proj with fused RMSNorm row-scale: out_seq bf16 -> xs
    k_mgemm<512, 256, true><<<dim3(2, 256), 256, 0, stream>>>(yg, 512, Wt_out, xs, DM_, 0, nullptr, scale);

    k_mgemm<256, 368, true><<<dim3(3, 256), 256, 0, stream>>>(xs, 256, Wt_un, tmp, KPATCH, 0, nullptr, nullptr);

    k_scatter<<<dim3(64, 184, 4), 256, 0, stream>>>(tmp, unemb_b, x, out);
}